// Round 5
// baseline (907.883 us; speedup 1.0000x reference)
//
#include <hip/hip_runtime.h>
#include <hip/hip_bf16.h>

// Problem constants (fixed-shape problem)
#define NN 262144      // nodes = 4096 graphs * 64
#define EE 2097152     // edges
#define BB 4096        // graphs
constexpr int INMLP = 6144;
constexpr int HID = 2048;
constexpr int HID4 = 512;
constexpr int OUTF = 256;
constexpr int NSL = 64;            // edge slices
constexpr int ESL = EE / NSL;      // 32768 edges per slice
constexpr int RNODES = 32768;      // nodes per range (8 ranges)

typedef short s16x8 __attribute__((ext_vector_type(8)));   // 8 bf16 in 4 VGPRs
typedef short s16x4 __attribute__((ext_vector_type(4)));
typedef float f32x4 __attribute__((ext_vector_type(4)));

__device__ __forceinline__ float lrelu(float v) { return v >= 0.f ? v : 0.01f * v; }
__device__ __forceinline__ float bf2f(short s) {
    unsigned int u = ((unsigned int)(unsigned short)s) << 16;
    return __builtin_bit_cast(float, u);
}
__device__ __forceinline__ short f2bf(float f) {   // RNE
    unsigned int u = __builtin_bit_cast(unsigned int, f);
    u = (u + 0x7fff + ((u >> 16) & 1)) >> 16;
    return (short)u;
}
// async global->LDS, 16B per lane. LDS dest = wave-uniform base + lane*16.
__device__ __forceinline__ void async16(const void* g, void* l) {
    __builtin_amdgcn_global_load_lds((__attribute__((address_space(1))) void*)g,
                                     (__attribute__((address_space(3))) void*)l, 16, 0, 0);
}

// ---------------- degree counting via LDS histograms (no global atomics) ----------------
__global__ __launch_bounds__(256) void hist_count(const int* __restrict__ dst, const int* __restrict__ src,
                                                  unsigned* __restrict__ part_din, unsigned* __restrict__ part_dout,
                                                  unsigned short* __restrict__ rankpack16) {
    __shared__ unsigned hist[RNODES / 2];   // 65536 B
    const int S = blockIdx.x & 63;
    const int R = (blockIdx.x >> 6) & 7;
    const int T = blockIdx.x >> 9;          // 0 = din(dst)+rank, 1 = dout(src)
    for (int i = threadIdx.x; i < RNODES / 2; i += 256) hist[i] = 0;
    __syncthreads();
    const int* idxarr = T ? src : dst;
    const int4* v4 = (const int4*)(idxarr + S * ESL);
#pragma unroll 4
    for (int i = 0; i < ESL / 4 / 256; i++) {            // 32 iterations
        const int q0 = i * 256 + threadIdx.x;
        int4 q = v4[q0];
        const int ebase = S * ESL + q0 * 4;
#pragma unroll
        for (int k = 0; k < 4; k++) {
            int idx = k == 0 ? q.x : k == 1 ? q.y : k == 2 ? q.z : q.w;
            if ((idx >> 15) == R) {
                int local = idx & (RNODES - 1);
                unsigned old = atomicAdd(&hist[local >> 1], 1u << ((local & 1) * 16));
                if (T == 0) {
                    unsigned rank = (old >> ((local & 1) * 16)) & 0xffffu;
                    rankpack16[ebase + k] = (unsigned short)((S << 10) | rank);   // rank < 1024
                }
            }
        }
    }
    __syncthreads();
    unsigned* dp = (T ? part_dout : part_din) + (size_t)S * (NN / 2) + R * (RNODES / 2);
    for (int i = threadIdx.x; i < RNODES / 2; i += 256) dp[i] = hist[i];
}

// ---------------- reduce slices: degrees, rsqrt factors, per-(slice,node) base offsets ----------------
__global__ __launch_bounds__(256) void deg_reduce(const unsigned* __restrict__ part_din,
                                                  const unsigned* __restrict__ part_dout,
                                                  unsigned* __restrict__ repbase_w,   // [NSL][NN/2] packed u16
                                                  float* __restrict__ ro, float* __restrict__ ri,
                                                  int* __restrict__ din) {
    int i = blockIdx.x * 256 + threadIdx.x;    // word index over NN/2
    unsigned runl = 0, runh = 0, dl = 0, dh = 0;
#pragma unroll 8
    for (int S = 0; S < NSL; S++) {
        repbase_w[(size_t)S * (NN / 2) + i] = (runl & 0xffffu) | (runh << 16);
        unsigned w = part_din[(size_t)S * (NN / 2) + i];
        runl += w & 0xffffu; runh += w >> 16;
        unsigned w2 = part_dout[(size_t)S * (NN / 2) + i];
        dl += w2 & 0xffffu; dh += w2 >> 16;
    }
    int n0 = 2 * i, n1 = 2 * i + 1;
    din[n0] = (int)runl; din[n1] = (int)runh;
    ro[n0] = rsqrtf((float)(dl < 1u ? 1u : dl));
    ro[n1] = rsqrtf((float)(dh < 1u ? 1u : dh));
    ri[n0] = rsqrtf((float)(runl < 1u ? 1u : runl));
    ri[n1] = rsqrtf((float)(runh < 1u ? 1u : runh));
}

// ---------------- scan (exclusive prefix over din counts -> CSR offsets) ----------------
__global__ __launch_bounds__(256) void scanA(const int* __restrict__ cnt, int* __restrict__ blks) {
    __shared__ int s[256];
    int t = threadIdx.x;
    int i0 = blockIdx.x * 1024 + t * 4;
    int ts = cnt[i0] + cnt[i0 + 1] + cnt[i0 + 2] + cnt[i0 + 3];
    s[t] = ts; __syncthreads();
    for (int d = 128; d > 0; d >>= 1) { if (t < d) s[t] += s[t + d]; __syncthreads(); }
    if (t == 0) blks[blockIdx.x] = s[0];
}

__global__ __launch_bounds__(256) void scanB(int* __restrict__ blks, int* __restrict__ offN) {
    __shared__ int s[256];
    int t = threadIdx.x;
    int v = blks[t]; s[t] = v; __syncthreads();
    for (int d = 1; d < 256; d <<= 1) {
        int x = (t >= d) ? s[t - d] : 0; __syncthreads();
        s[t] += x; __syncthreads();
    }
    blks[t] = s[t] - v;            // exclusive
    if (t == 255) *offN = s[255];  // total = EE
}

__global__ __launch_bounds__(256) void scanC(const int* __restrict__ cnt, const int* __restrict__ blkoff,
                                             int* __restrict__ off) {
    __shared__ int s[256];
    int t = threadIdx.x;
    int i0 = blockIdx.x * 1024 + t * 4;
    int v0 = cnt[i0], v1 = cnt[i0 + 1], v2 = cnt[i0 + 2], v3 = cnt[i0 + 3];
    int ts = v0 + v1 + v2 + v3;
    s[t] = ts; __syncthreads();
    for (int d = 1; d < 256; d <<= 1) {
        int x = (t >= d) ? s[t - d] : 0; __syncthreads();
        s[t] += x; __syncthreads();
    }
    int base = blkoff[blockIdx.x] + (s[t] - ts);
    off[i0] = base; off[i0 + 1] = base + v0; off[i0 + 2] = base + v0 + v1; off[i0 + 3] = base + v0 + v1 + v2;
}

// ---------------- fill CSR: atomic-free scatter via (slice, rank) + repbase ----------------
__global__ __launch_bounds__(256) void fill_csr(const int* __restrict__ src, const int* __restrict__ dst,
                                                const float* __restrict__ ew, const float* __restrict__ ro,
                                                const int* __restrict__ off,
                                                const unsigned short* __restrict__ repbase16,  // [NSL][NN]
                                                const unsigned short* __restrict__ rankpack16,
                                                int2* __restrict__ edg) {
    int e = blockIdx.x * 256 + threadIdx.x;
    int d = dst[e];
    int s = src[e];
    unsigned pk = rankpack16[e];
    int S = pk >> 10, rank = pk & 1023;
    int p = off[d] + (int)repbase16[(size_t)S * NN + d] + rank;
    edg[p] = make_int2(s, __builtin_bit_cast(int, ew[e] * ro[s]));
}

// ---------------- x fp32 -> bf16 ----------------
__global__ __launch_bounds__(256) void cvt_x(const float* __restrict__ X, short* __restrict__ Xb) {
    int i = (blockIdx.x * 256 + threadIdx.x) * 4;
    float4 v = *(const float4*)(X + i);
    s16x4 o = { f2bf(v.x), f2bf(v.y), f2bf(v.z), f2bf(v.w) };
    *(s16x4*)(Xb + i) = o;
}

// ---------------- conv1 fused: gather64 -> LDS A-tile -> MFMA + GraphNorm1 (block = 128 nodes) ----------------
// Gather phase: wave w gathers nodes bm+w*32..+31 (edge-parallel 8 edges x 8 chunks, identical math to
// the former gather64, f2bf rounding preserved), writing bf16 rows straight into As. Then the verified
// conv1_gn MFMA+norm phase runs unchanged. Saves the aggx HBM round-trip (64 MB).
__global__ __launch_bounds__(256) void conv1_gather_gn(const short* __restrict__ Xb, const int* __restrict__ offs,
                                                       const int2* __restrict__ edg, const short* __restrict__ BT,
                                                       const float* __restrict__ ri,
                                                       const float* __restrict__ alpha, const float* __restrict__ gamma,
                                                       const float* __restrict__ beta, short* __restrict__ Outp) {
    __shared__ short As[128][72];
    __shared__ short Bs[128][72];
    __shared__ float sscale[2][128], sshift[2][128];
    const int t = threadIdx.x;
    const int bm = blockIdx.x * 128;
    const int wave = t >> 6, lane = t & 63;
    const int wm = (wave & 1) * 64, wn = (wave >> 1) * 64;
    const int g = wave & 1;
    const int m16 = lane & 15, quad = lane >> 4;
    // stage B (W1T, 128x64)
#pragma unroll
    for (int i = 0; i < 4; i++) {
        int idx = t + 256 * i;
        int rr = idx >> 3, kk = (idx & 7) * 8;
        *(s16x8*)&Bs[rr][kk] = *(const s16x8*)&BT[(size_t)rr * 64 + kk];
    }
    // gather 32 nodes per wave into As
    {
        const int e = lane >> 3, c = lane & 7;
        for (int i = 0; i < 32; i++) {
            const int row = wave * 32 + i;
            const int node = bm + row;
            const int s0 = offs[node], s1 = offs[node + 1];
            float acc[8] = {};
            for (int j0 = s0; j0 < s1; j0 += 8) {
                int j = j0 + e;
                bool ok = j < s1;
                int2 pe = edg[ok ? j : s0];
                int s = pe.x;
                float w = ok ? __builtin_bit_cast(float, pe.y) : 0.f;
                s16x8 v = *(const s16x8*)&Xb[(size_t)s * 64 + c * 8];
#pragma unroll
                for (int k = 0; k < 8; k++) acc[k] = fmaf(w, bf2f(v[k]), acc[k]);
            }
#pragma unroll
            for (int off = 8; off <= 32; off <<= 1)
#pragma unroll
                for (int k = 0; k < 8; k++) acc[k] += __shfl_xor(acc[k], off);
            if (e == 0) {
                s16x8 o;
#pragma unroll
                for (int k = 0; k < 8; k++) o[k] = f2bf(acc[k]);
                *(s16x8*)&As[row][c * 8] = o;
            }
        }
    }
    __syncthreads();
    f32x4 acc[4][4] = {};
#pragma unroll
    for (int kc = 0; kc < 2; kc++) {
        s16x8 af[4], bfr[4];
#pragma unroll
        for (int mt = 0; mt < 4; mt++) af[mt] = *(const s16x8*)&As[wm + mt * 16 + m16][kc * 32 + quad * 8];
#pragma unroll
        for (int nt = 0; nt < 4; nt++) bfr[nt] = *(const s16x8*)&Bs[wn + nt * 16 + m16][kc * 32 + quad * 8];
#pragma unroll
        for (int mt = 0; mt < 4; mt++)
#pragma unroll
            for (int nt = 0; nt < 4; nt++)
                acc[mt][nt] = __builtin_amdgcn_mfma_f32_16x16x32_bf16(af[mt], bfr[nt], acc[mt][nt], 0, 0, 0);
    }
#pragma unroll
    for (int mt = 0; mt < 4; mt++)
#pragma unroll
        for (int r4 = 0; r4 < 4; r4++) {
            float rv = ri[bm + wm + mt * 16 + quad * 4 + r4];
#pragma unroll
            for (int nt = 0; nt < 4; nt++)
                acc[mt][nt][r4] = lrelu(acc[mt][nt][r4] * rv);
        }
#pragma unroll
    for (int nt = 0; nt < 4; nt++) {
        float s1 = 0.f, s2 = 0.f;
#pragma unroll
        for (int mt = 0; mt < 4; mt++)
#pragma unroll
            for (int r4 = 0; r4 < 4; r4++) { float v = acc[mt][nt][r4]; s1 += v; s2 += v * v; }
        s1 += __shfl_xor(s1, 16); s1 += __shfl_xor(s1, 32);
        s2 += __shfl_xor(s2, 16); s2 += __shfl_xor(s2, 32);
        if (quad == 0) {
            int ch = wn + nt * 16 + m16;
            float m = s1 * (1.f / 64.f);
            float a = alpha[ch];
            float var = s2 * (1.f / 64.f) - m * m * a * (2.f - a);   // E[(v-am)^2]
            float sc = gamma[ch] * rsqrtf(var + 1e-5f);
            sscale[g][ch] = sc;
            sshift[g][ch] = beta[ch] - sc * a * m;
        }
    }
    __syncthreads();
#pragma unroll
    for (int nt = 0; nt < 4; nt++) {
        int ch = wn + nt * 16 + m16;
        float sc = sscale[g][ch], sh = sshift[g][ch];
#pragma unroll
        for (int mt = 0; mt < 4; mt++)
#pragma unroll
            for (int r4 = 0; r4 < 4; r4++) {
                int row = bm + wm + mt * 16 + quad * 4 + r4;
                Outp[(size_t)row * 128 + ch] = f2bf(sc * acc[mt][nt][r4] + sh);
            }
    }
}

// ---------------- conv2: MFMA GEMM 262144x96x128, A=gn1 bf16, BT=W2T bf16 (96x128), out h2 bf16 ----------------
__global__ __launch_bounds__(256) void conv2_mfma(const short* __restrict__ A, const short* __restrict__ BT,
                                                  short* __restrict__ H) {
    __shared__ short As[128][136];   // 128 k + 8 pad
    __shared__ short Bs[96][136];
    const int t = threadIdx.x;
    const int bm = blockIdx.x * 128;
    const int wave = t >> 6, lane = t & 63;
    const int wm = (wave & 1) * 64, wn = (wave >> 1) * 48;
    const int m16 = lane & 15, quad = lane >> 4;
#pragma unroll
    for (int i = 0; i < 8; i++) {
        int idx = t + 256 * i;
        int rr = idx >> 4, kk = (idx & 15) * 8;
        *(s16x8*)&As[rr][kk] = *(const s16x8*)&A[(size_t)(bm + rr) * 128 + kk];
    }
#pragma unroll
    for (int i = 0; i < 6; i++) {
        int idx = t + 256 * i;
        int nr = idx >> 4, kk = (idx & 15) * 8;
        *(s16x8*)&Bs[nr][kk] = *(const s16x8*)&BT[(size_t)nr * 128 + kk];
    }
    __syncthreads();
    f32x4 acc[4][3] = {};
#pragma unroll
    for (int kc = 0; kc < 4; kc++) {
        s16x8 af[4], bfr[3];
#pragma unroll
        for (int mt = 0; mt < 4; mt++) af[mt] = *(const s16x8*)&As[wm + mt * 16 + m16][kc * 32 + quad * 8];
#pragma unroll
        for (int nt = 0; nt < 3; nt++) bfr[nt] = *(const s16x8*)&Bs[wn + nt * 16 + m16][kc * 32 + quad * 8];
#pragma unroll
        for (int mt = 0; mt < 4; mt++)
#pragma unroll
            for (int nt = 0; nt < 3; nt++)
                acc[mt][nt] = __builtin_amdgcn_mfma_f32_16x16x32_bf16(af[mt], bfr[nt], acc[mt][nt], 0, 0, 0);
    }
#pragma unroll
    for (int mt = 0; mt < 4; mt++)
#pragma unroll
        for (int r4 = 0; r4 < 4; r4++) {
            int row = bm + wm + mt * 16 + quad * 4 + r4;
#pragma unroll
            for (int nt = 0; nt < 3; nt++)
                H[(size_t)row * 96 + wn + nt * 16 + m16] = f2bf(acc[mt][nt][r4]);
        }
}

// ---------------- gather96 + GraphNorm2 fused: block = 1 graph (64 nodes), agg2 never hits HBM ----------------
// Gather math identical to former gather96 (incl. f2bf round-trip before *ri), stats identical to
// graphnorm_k<96>. Saves the agg2 HBM round-trip (96 MB).
__global__ __launch_bounds__(256) void gather96_gn(const short* __restrict__ H, const int* __restrict__ offs,
                                                   const int2* __restrict__ edg, const float* __restrict__ ri,
                                                   const float* __restrict__ alpha, const float* __restrict__ gamma,
                                                   const float* __restrict__ beta, short* __restrict__ Out) {
    __shared__ float sm[64 * 96];       // 24 KiB
    __shared__ float sscale[96], sshift[96];
    const int g = blockIdx.x;
    const int t = threadIdx.x;
    const int wave = t >> 6, lane = t & 63;
    const int e = lane >> 4, c = lane & 15;
    for (int i = 0; i < 16; i++) {
        const int row = wave * 16 + i;
        const int node = g * 64 + row;
        const int s0 = offs[node], s1 = offs[node + 1];
        float acc[6] = {};
        for (int j0 = s0; j0 < s1; j0 += 4) {
            int j = j0 + e;
            bool ok = j < s1;
            int2 pe = edg[ok ? j : s0];
            int s = pe.x;
            float w = ok ? __builtin_bit_cast(float, pe.y) : 0.f;
            const unsigned int* hp = (const unsigned int*)(H + (size_t)s * 96 + c * 6);
            unsigned int u0 = hp[0], u1 = hp[1], u2 = hp[2];
            acc[0] = fmaf(w, bf2f((short)(u0 & 0xffff)), acc[0]);
            acc[1] = fmaf(w, bf2f((short)(u0 >> 16)), acc[1]);
            acc[2] = fmaf(w, bf2f((short)(u1 & 0xffff)), acc[2]);
            acc[3] = fmaf(w, bf2f((short)(u1 >> 16)), acc[3]);
            acc[4] = fmaf(w, bf2f((short)(u2 & 0xffff)), acc[4]);
            acc[5] = fmaf(w, bf2f((short)(u2 >> 16)), acc[5]);
        }
#pragma unroll
        for (int off = 16; off <= 32; off <<= 1)
#pragma unroll
            for (int k = 0; k < 6; k++) acc[k] += __shfl_xor(acc[k], off);
        if (e == 0) {
            float rv = ri[node];
#pragma unroll
            for (int k = 0; k < 6; k++)
                sm[row * 96 + c * 6 + k] = lrelu(bf2f(f2bf(acc[k])) * rv);
        }
    }
    __syncthreads();
    if (t < 96) {
        int c2 = t;
        float s1 = 0.f, s2 = 0.f;
#pragma unroll 4
        for (int i = 0; i < 64; i++) { float v = sm[i * 96 + c2]; s1 += v; s2 += v * v; }
        float m = s1 * (1.f / 64.f);
        float a = alpha[c2];
        float var = s2 * (1.f / 64.f) - m * m * a * (2.f - a);   // E[(v-am)^2]
        float sc = gamma[c2] * rsqrtf(var + 1e-5f);
        sscale[c2] = sc;
        sshift[c2] = beta[c2] - sc * a * m;
    }
    __syncthreads();
    const size_t base = (size_t)g * 64 * 96;
    for (int idx = t; idx < 64 * 96; idx += 256) {
        int c2 = idx % 96;
        Out[base + idx] = f2bf(sscale[c2] * sm[idx] + sshift[c2]);
    }
}

// ---------------- W fp32 (R x Cc) -> WT bf16 (Cc x R), tiled transpose+convert ----------------
__global__ __launch_bounds__(256) void transp_cvt(const float* __restrict__ W, short* __restrict__ WT,
                                                  int R, int Cc) {
    __shared__ short tile[32][33];
    const int bc = blockIdx.x * 32;   // col of W
    const int br = blockIdx.y * 32;   // row of W
    const int tx = threadIdx.x & 31, ty = threadIdx.x >> 5;   // 32 x 8
#pragma unroll
    for (int i = 0; i < 32; i += 8)
        tile[ty + i][tx] = f2bf(W[(size_t)(br + ty + i) * Cc + bc + tx]);
    __syncthreads();
#pragma unroll
    for (int i = 0; i < 32; i += 8)
        WT[(size_t)(bc + ty + i) * R + br + tx] = tile[tx][ty + i];
}

// ---------------- MLP1: 256x256-tile 8-phase split-K bf16 MFMA GEMM (round-2 verified, 129 us) ----------------
#define MBAR() __builtin_amdgcn_s_barrier()
#define LGKM0() asm volatile("s_waitcnt lgkmcnt(0)" ::: "memory")
#define SB0() __builtin_amdgcn_sched_barrier(0)
#define VMC4() asm volatile("s_waitcnt vmcnt(4)" ::: "memory")
#define VMC2() asm volatile("s_waitcnt vmcnt(2)" ::: "memory")
#define VMC0() asm volatile("s_waitcnt vmcnt(0)" ::: "memory")

__global__ __launch_bounds__(512, 2) void mlp1_mfma8(const short* __restrict__ A, const short* __restrict__ BT,
                                                     short* __restrict__ Cp) {
    constexpr int K = INMLP;
    __shared__ short As[2][256 * 64];
    __shared__ short Bs[2][256 * 64];
    const int t = threadIdx.x;
    const int wid = t >> 6, lane = t & 63;
    const int lrow = lane >> 3, lcol = lane & 7;
    const int scol = lcol ^ (lrow & 7);
    const int m16 = lane & 15, quad = lane >> 4, xkey = m16 & 7;
    const int wm = wid & 1, wn = wid >> 1;
    const int sw = (blockIdx.x & 7) * 32 + (blockIdx.x >> 3);
    const int bm = sw & 15, bn = (sw >> 4) & 7, z = sw >> 7;
    const short* gA = A + (size_t)(bm * 256 + lrow) * K + (size_t)z * (K / 2) + scol * 8;
    const short* gB = BT + (size_t)(bn * 256 + lrow) * K + (size_t)z * (K / 2) + scol * 8;

    f32x4 acc[8][4] = {};

#define STG(gp, Xs, s, r0, ko) \
    async16(gp + (size_t)((r0) + wid * 8) * K + (ko), &Xs[s][((r0) + wid * 8) * 64])
#define STAGE_B4(s, ko) { STG(gB, Bs, s, 0, ko); STG(gB, Bs, s, 64, ko); STG(gB, Bs, s, 128, ko); STG(gB, Bs, s, 192, ko); }
#define STAGE_A4(s, ko) { STG(gA, As, s, 0, ko); STG(gA, As, s, 128, ko); STG(gA, As, s, 64, ko); STG(gA, As, s, 192, ko); }
#define PH_LOAD(s, kc, mh) \
    { _Pragma("unroll") for (int mt = 0; mt < 4; mt++) \
          af[mt] = *(const s16x8*)&As[s][(wm * 128 + (mh) * 64 + mt * 16 + m16) * 64 + (((kc) * 4 + quad) ^ xkey) * 8]; \
      _Pragma("unroll") for (int nt = 0; nt < 4; nt++) \
          bfr[nt] = *(const s16x8*)&Bs[s][(wn * 64 + nt * 16 + m16) * 64 + (((kc) * 4 + quad) ^ xkey) * 8]; }
#define PH_MM(mh) \
    { _Pragma("unroll") for (int mt = 0; mt < 4; mt++) \
          _Pragma("unroll") for (int nt = 0; nt < 4; nt++) \
              acc[(mh) * 4 + mt][nt] = __builtin_amdgcn_mfma_f32_16x16x32_bf16(af[mt], bfr[nt], acc[(mh) * 4 + mt][nt], 0, 0, 0); }

    STAGE_B4(0, 0); STAGE_A4(0, 0);
    VMC2();
    MBAR();

    int kof = 0;
#pragma unroll 1
    for (int i = 0; i < 24; i++, kof += 128) {
        const bool st = (i < 23);
        s16x8 af[4], bfr[4];
        // ph1
        PH_LOAD(0, 0, 0); STAGE_B4(1, kof + 64);
        MBAR(); LGKM0(); SB0();
        __builtin_amdgcn_s_setprio(1); PH_MM(0); __builtin_amdgcn_s_setprio(0);
        VMC4(); MBAR();
        // ph2
        PH_LOAD(0, 0, 1); STAGE_A4(1, kof + 64);
        MBAR(); LGKM0(); SB0();
        __builtin_amdgcn_s_setprio(1); PH_MM(1); __builtin_amdgcn_s_setprio(0);
        MBAR();
        // ph3
        PH_LOAD(0, 1, 0);
        MBAR(); LGKM0(); SB0();
        __builtin_amdgcn_s_setprio(1); PH_MM(0); __builtin_amdgcn_s_setprio(0);
        MBAR();
        // ph4
        PH_LOAD(0, 1, 1);
        MBAR(); LGKM0(); SB0();
        __builtin_amdgcn_s_setprio(1); PH_MM(1); __builtin_amdgcn_s_setprio(0);
        VMC2(); MBAR();
        // ph5
        PH_LOAD(1, 0, 0);
        if (st) STAGE_B4(0, kof + 128);
        MBAR(); LGKM0(); SB0();
        __builtin_amdgcn_s_setprio(1); PH_MM(0); __builtin_amdgcn_s_setprio(0);
        if (st) { VMC4(); } else { VMC0(); }
        MBAR();
        // ph6
        PH_LOAD(1, 0, 1);
        if (st) STAGE_A4(0, kof + 128);
        MBAR(); LGKM0(); SB0();
        __builtin_amdgcn_s_setprio(1); PH_MM(1); __builtin_amdgcn_s_setprio(0);
        MBAR();
        // ph7
        PH_LOAD(1, 1, 0);
        MBAR(); LGKM0(); SB0();
        __builtin_amdgcn_s_setprio(1); PH_MM(0); __builtin_amdgcn_s_setprio(0);
        MBAR();
        // ph8
        PH_LOAD(1, 1, 1);
        MBAR(); LGKM0(); SB0();
        __builtin_amdgcn_s_setprio(1); PH_MM(1); __builtin_amdgcn_s_setprio(0);
        if (st) { VMC2(); }
        MBAR();
    }

    short* C = Cp + (size_t)z * BB * HID;
    const int r0 = bm * 256 + wm * 128 + quad * 4;
    const int c0 = bn * 256 + wn * 64 + m16;
#pragma unroll
    for (int mt = 0; mt < 8; mt++)
#pragma unroll
        for (int nt = 0; nt < 4; nt++)
#pragma unroll
            for (int r4 = 0; r4 < 4; r4++)
                C[(size_t)(r0 + mt * 16 + r4) * HID + c0 + nt * 16] = f2bf(acc[mt][nt][r4]);
#undef STG
#undef STAGE_A4
#undef STAGE_B4
#undef PH_LOAD
#undef PH_MM
}

// ---------------- combine split-K partials + leaky + InstanceNorm, bf16 in place (D0) ----------------
__global__ __launch_bounds__(256) void rownorm_hid(short* __restrict__ D0, const short* __restrict__ D1) {
    const size_t base = (size_t)blockIdx.x * HID;
    float v[8];
    float s1 = 0.f, s2 = 0.f;
    const int c0 = threadIdx.x * 8;
    {
        s16x8 a = *(const s16x8*)&D0[base + c0];
        s16x8 b = *(const s16x8*)&D1[base + c0];
#pragma unroll
        for (int k = 0; k < 8; k++) {
            float x = lrelu(bf2f(a[k]) + bf2f(b[k]));
            v[k] = x; s1 += x; s2 += x * x;
        }
    }
#pragma unroll
    for (int o = 32; o > 0; o >>= 1) { s1 += __shfl_down(s1, o); s2 += __shfl_down(s2, o); }
    __shared__ float w1[4], w2[4];
    if ((threadIdx.x & 63) == 0) { w1[threadIdx.x >> 6] = s1; w2[threadIdx.x >> 6] = s2; }
    __syncthreads();
    s1 = w1[0] + w1[1] + w1[2] + w1[3];
    s2 = w2[0] + w2[1] + w2[2] + w2[3];
    float m = s1 * (1.f / HID);
    float inv = rsqrtf(s2 * (1.f / HID) - m * m + 1e-5f);
    s16x8 o;
#pragma unroll
    for (int k = 0; k < 8; k++) o[k] = f2bf((v[k] - m) * inv);
    *(s16x8*)&D0[base + c0] = o;
}

// ---------------- generic MFMA GEMM: A bf16 or fp32 (converted on stage), BT bf16, C fp32 ----------------
template <bool ABF16, bool LEAKY>
__global__ __launch_bounds__(256) void mfma_gemm(const float* __restrict__ Af, const short* __restrict__ Ab,
                                                 const short* __restrict__ BT,
                                                 float* __restrict__ C, int M, int Nn, int K) {
    __shared__ short As[64][40];
    __shared__ short Bs[64][40];
    const int t = threadIdx.x;
    const int bm = blockIdx.x * 64, bn = blockIdx.y * 64;
    const int wave = t >> 6, lane = t & 63;
    const int wm = (wave & 1) * 32, wn = (wave >> 1) * 32;
    const int m16 = lane & 15, quad = lane >> 4;
    const int rr = t >> 2, kk = (t & 3) * 8;
    f32x4 acc[2][2] = {};
    for (int k0 = 0; k0 < K; k0 += 32) {
        if (ABF16) {
            *(s16x8*)&As[rr][kk] = *(const s16x8*)&Ab[(size_t)(bm + rr) * K + k0 + kk];
        } else {
            const float* ap = &Af[(size_t)(bm + rr) * K + k0 + kk];
            float4 v0 = *(const float4*)ap;
            float4 v1 = *(const float4*)(ap + 4);
            s16x8 a8;
            a8[0] = f2bf(v0.x); a8[1] = f2bf(v0.y); a8[2] = f2bf(v0.z); a8[3] = f2bf(v0.w);
            a8[4] = f2bf(v1.x); a8[5] = f2bf(v1.y); a8[6] = f2bf(v1.z); a8[7] = f2bf(v1.w);
            *(s16x8*)&As[rr][kk] = a8;
        }
        *(s16x8*)&Bs[rr][kk] = *(const s16x8*)&BT[(size_t)(bn + rr) * K + k0 + kk];
        __syncthreads();
        s16x8 af[2], bfr[2];
#pragma unroll
        for (int mt = 0; mt < 2; mt++) af[mt] = *(const s16x8*)&As[wm + mt * 16 + m16][quad * 8];
#pragma unroll
        for (int nt = 0; nt < 2; nt++) bfr[nt] = *(const s16x8*)&Bs[wn + nt * 16 + m16][quad * 8];
#pragma unroll
        for (int mt = 0; mt < 2; mt++)
#pragma unroll
            for (int nt = 0; nt < 2; nt++)
                acc[mt][nt] = __builtin_amdgcn_mfma_f32_16x16x32_bf16(af[mt], bfr[nt], acc[mt][nt], 0, 0, 0);
        __syncthreads();
    }
#pragma unroll
    for (int mt = 0; mt < 2; mt++)
#pragma unroll
        for (int nt = 0; nt < 2; nt++)
#pragma unroll
            for (int r4 = 0; r4 < 4; r4++) {
                int row = bm + wm + mt * 16 + quad * 4 + r4;
                int col = bn + wn + nt * 16 + m16;
                float v = acc[mt][nt][r4];
                if (LEAKY) v = lrelu(v);
                C[(size_t)row * Nn + col] = v;
            }
}

// ---------------- per-row InstanceNorm (in place, fp32) ----------------
template <int NC>
__global__ __launch_bounds__(256) void rownorm(float* __restrict__ Y) {
    float* p = Y + (size_t)blockIdx.x * NC;
    float s1 = 0.f, s2 = 0.f;
    for (int c = threadIdx.x; c < NC; c += 256) { float v = p[c]; s1 += v; s2 += v * v; }
#pragma unroll
    for (int o = 32; o > 0; o >>= 1) { s1 += __shfl_down(s1, o); s2 += __shfl_down(s2, o); }
    __shared__ float w1[4], w2[4];
    if ((threadIdx.x & 63) == 0) { w1[threadIdx.x >> 6] = s1; w2[threadIdx.x >> 6] = s2; }
    __syncthreads();
    s1 = w1[0] + w1[1] + w1[2] + w1[3];
    s2 = w2[0] + w2[1] + w2[2] + w2[3];
    float m = s1 * (1.f / NC);
    float inv = rsqrtf(s2 * (1.f / NC) - m * m + 1e-5f);
    for (int c = threadIdx.x; c < NC; c += 256) p[c] = (p[c] - m) * inv;
}

extern "C" void kernel_launch(void* const* d_in, const int* in_sizes, int n_in,
                              void* d_out, int out_size, void* d_ws, size_t ws_size,
                              hipStream_t stream) {
    const float* x    = (const float*)d_in[0];
    const float* ew   = (const float*)d_in[1];
    const int*   src  = (const int*)d_in[2];
    const int*   dst  = (const int*)d_in[3];
    const float* W1   = (const float*)d_in[4];
    const float* W2   = (const float*)d_in[5];
    const float* a1   = (const float*)d_in[6];
    const float* g1   = (const float*)d_in[7];
    const float* b1   = (const float*)d_in[8];
    const float* a2   = (const float*)d_in[9];
    const float* g2   = (const float*)d_in[10];
    const float* b2   = (const float*)d_in[11];
    const float* Win  = (const float*)d_in[12];
    const float* Whid = (const float*)d_in[13];
    const float* Wcls = (const float*)d_in[14];
    float* out = (float*)d_out;

    // ---- workspace layout ----
    float* ro   = (float*)d_ws;                    // NN
    float* ri   = ro + NN;                         // NN
    int*   din  = (int*)(ri + NN);                 // NN (deg_in for scan)
    int*   offs = din + NN;                        // NN+4
    int*   blks = offs + NN + 4;                   // 256
    short* w1t  = (short*)(blks + 256);            // 128*64 bf16
    short* w2t  = w1t + 128 * 64;                  // 96*128 bf16
    int2*  edg  = (int2*)(((size_t)(w2t + 96 * 128) + 15) & ~(size_t)15);   // EE int2 (src, ew*ro), 16.8 MB
    short* Abf  = (short*)(edg + EE);              // 64 MiB region
    short* Bbf  = Abf + (size_t)NN * 128;          // 64 MiB region
    short* xbf  = Abf;                             // NN*64
    // graph-build temps: part arrays fill Abf; repbase+rank in Bbf
    unsigned*       part_din   = (unsigned*)Abf;                       // NSL * NN/2 words (32 MiB)
    unsigned*       part_dout  = part_din + (size_t)NSL * (NN / 2);    // 32 MiB
    unsigned*       repbase_w  = (unsigned*)Bbf;                       // 32 MiB
    unsigned short* rankpack16 = (unsigned short*)(repbase_w + (size_t)NSL * (NN / 2));  // EE u16
    // overlays into Abf region after gather96_gn (h2 dead):
    short* WinT = Abf;                                      // 2048*6144 bf16 = 25165824 B
    short* D0   = (short*)((char*)Abf + 25165824);          // 4096*2048 bf16 = 16777216 B
    short* D1   = D0 + (size_t)BB * HID;                    // 4096*2048 bf16 = 16777216 B  (total 58.7 MB <= 64 MiB)
    // Y2 in edg region (edg dead after gather96_gn):
    float* Y2   = (float*)edg;                              // 4096*512 fp32 = 8388608 B <= 16.8 MB
    // overlays into Bbf region after mlp1_mfma8 consumes gn2:
    short* WhidT = Bbf;                            // 512*2048 bf16
    short* WclsT = WhidT + (size_t)HID4 * HID;     // 256*512 bf16

    // 1) degrees + per-edge ranks via LDS histograms (1024 blocks, int4 streaming)
    hist_count<<<2 * 8 * NSL, 256, 0, stream>>>(dst, src, part_din, part_dout, rankpack16);
    deg_reduce<<<NN / 512, 256, 0, stream>>>(part_din, part_dout, repbase_w, ro, ri, din);

    // 2) CSR by dst: scan + atomic-free fill
    scanA<<<NN / 1024, 256, 0, stream>>>(din, blks);
    scanB<<<1, 256, 0, stream>>>(blks, offs + NN);
    scanC<<<NN / 1024, 256, 0, stream>>>(din, blks, offs);
    fill_csr<<<EE / 256, 256, 0, stream>>>(src, dst, ew, ro, offs,
                                           (const unsigned short*)repbase_w, rankpack16, edg);

    // 3) conv layer 1: fused gather64 + GEMM + GraphNorm1
    cvt_x<<<NN * 64 / 1024, 256, 0, stream>>>(x, xbf);
    transp_cvt<<<dim3(128 / 32, 64 / 32), 256, 0, stream>>>(W1, w1t, 64, 128);
    conv1_gather_gn<<<NN / 128, 256, 0, stream>>>(xbf, offs, edg, w1t, ri, a1, g1, b1, Bbf);   // Bbf = gn1

    // 4) conv layer 2: GEMM, then fused gather96 + GraphNorm2
    transp_cvt<<<dim3(96 / 32, 128 / 32), 256, 0, stream>>>(W2, w2t, 128, 96);
    conv2_mfma<<<NN / 128, 256, 0, stream>>>(Bbf, w2t, Abf);                  // h2 (xbf dead)
    gather96_gn<<<BB, 256, 0, stream>>>(Abf, offs, edg, ri, a2, g2, b2, Bbf); // Bbf = gn2 (MLP input)

    // 5) MLP
    transp_cvt<<<dim3(HID / 32, INMLP / 32), 256, 0, stream>>>(Win, WinT, INMLP, HID);
    mlp1_mfma8<<<256, 512, 0, stream>>>(Bbf, WinT, D0);                       // 8-phase split-K partials
    transp_cvt<<<dim3(HID4 / 32, HID / 32), 256, 0, stream>>>(Whid, WhidT, HID, HID4);
    transp_cvt<<<dim3(OUTF / 32, HID4 / 32), 256, 0, stream>>>(Wcls, WclsT, HID4, OUTF);
    rownorm_hid<<<BB, 256, 0, stream>>>(D0, D1);                                  // D0 = norm(lrelu(D0+D1)) bf16
    mfma_gemm<true, true><<<dim3(BB / 64, HID4 / 64), 256, 0, stream>>>(nullptr, D0, WhidT, Y2, BB, HID4, HID);
    rownorm<HID4><<<BB, 256, 0, stream>>>(Y2);
    mfma_gemm<false, false><<<dim3(BB / 64, OUTF / 64), 256, 0, stream>>>(Y2, nullptr, WclsT, out, BB, OUTF, HID4);
}

// Round 6
// 806.523 us; speedup vs baseline: 1.1257x; 1.1257x over previous
//
#include <hip/hip_runtime.h>
#include <hip/hip_bf16.h>

// Problem constants (fixed-shape problem)
#define NN 262144      // nodes = 4096 graphs * 64
#define EE 2097152     // edges
#define BB 4096        // graphs
constexpr int INMLP = 6144;
constexpr int HID = 2048;
constexpr int HID4 = 512;
constexpr int OUTF = 256;
constexpr int NSL = 64;            // edge slices
constexpr int ESL = EE / NSL;      // 32768 edges per slice
constexpr int RNODES = 32768;      // nodes per range (8 ranges)

typedef short s16x8 __attribute__((ext_vector_type(8)));   // 8 bf16 in 4 VGPRs
typedef short s16x4 __attribute__((ext_vector_type(4)));
typedef float f32x4 __attribute__((ext_vector_type(4)));

__device__ __forceinline__ float lrelu(float v) { return v >= 0.f ? v : 0.01f * v; }
__device__ __forceinline__ float bf2f(short s) {
    unsigned int u = ((unsigned int)(unsigned short)s) << 16;
    return __builtin_bit_cast(float, u);
}
__device__ __forceinline__ short f2bf(float f) {   // RNE
    unsigned int u = __builtin_bit_cast(unsigned int, f);
    u = (u + 0x7fff + ((u >> 16) & 1)) >> 16;
    return (short)u;
}
// async global->LDS, 16B per lane. LDS dest = wave-uniform base + lane*16.
__device__ __forceinline__ void async16(const void* g, void* l) {
    __builtin_amdgcn_global_load_lds((__attribute__((address_space(1))) void*)g,
                                     (__attribute__((address_space(3))) void*)l, 16, 0, 0);
}

// ---------------- degree counting via LDS histograms (no global atomics) ----------------
__global__ __launch_bounds__(256) void hist_count(const int* __restrict__ dst, const int* __restrict__ src,
                                                  unsigned* __restrict__ part_din, unsigned* __restrict__ part_dout,
                                                  unsigned short* __restrict__ rankpack16) {
    __shared__ unsigned hist[RNODES / 2];   // 65536 B
    const int S = blockIdx.x & 63;
    const int R = (blockIdx.x >> 6) & 7;
    const int T = blockIdx.x >> 9;          // 0 = din(dst)+rank, 1 = dout(src)
    for (int i = threadIdx.x; i < RNODES / 2; i += 256) hist[i] = 0;
    __syncthreads();
    const int* idxarr = T ? src : dst;
    const int4* v4 = (const int4*)(idxarr + S * ESL);
#pragma unroll 4
    for (int i = 0; i < ESL / 4 / 256; i++) {            // 32 iterations
        const int q0 = i * 256 + threadIdx.x;
        int4 q = v4[q0];
        const int ebase = S * ESL + q0 * 4;
#pragma unroll
        for (int k = 0; k < 4; k++) {
            int idx = k == 0 ? q.x : k == 1 ? q.y : k == 2 ? q.z : q.w;
            if ((idx >> 15) == R) {
                int local = idx & (RNODES - 1);
                unsigned old = atomicAdd(&hist[local >> 1], 1u << ((local & 1) * 16));
                if (T == 0) {
                    unsigned rank = (old >> ((local & 1) * 16)) & 0xffffu;
                    rankpack16[ebase + k] = (unsigned short)((S << 10) | rank);   // rank < 1024
                }
            }
        }
    }
    __syncthreads();
    unsigned* dp = (T ? part_dout : part_din) + (size_t)S * (NN / 2) + R * (RNODES / 2);
    for (int i = threadIdx.x; i < RNODES / 2; i += 256) dp[i] = hist[i];
}

// ---------------- reduce slices: degrees, rsqrt factors, per-(slice,node) base offsets ----------------
__global__ __launch_bounds__(256) void deg_reduce(const unsigned* __restrict__ part_din,
                                                  const unsigned* __restrict__ part_dout,
                                                  unsigned* __restrict__ repbase_w,   // [NSL][NN/2] packed u16
                                                  float* __restrict__ ro, float* __restrict__ ri,
                                                  int* __restrict__ din) {
    int i = blockIdx.x * 256 + threadIdx.x;    // word index over NN/2
    unsigned runl = 0, runh = 0, dl = 0, dh = 0;
#pragma unroll 8
    for (int S = 0; S < NSL; S++) {
        repbase_w[(size_t)S * (NN / 2) + i] = (runl & 0xffffu) | (runh << 16);
        unsigned w = part_din[(size_t)S * (NN / 2) + i];
        runl += w & 0xffffu; runh += w >> 16;
        unsigned w2 = part_dout[(size_t)S * (NN / 2) + i];
        dl += w2 & 0xffffu; dh += w2 >> 16;
    }
    int n0 = 2 * i, n1 = 2 * i + 1;
    din[n0] = (int)runl; din[n1] = (int)runh;
    ro[n0] = rsqrtf((float)(dl < 1u ? 1u : dl));
    ro[n1] = rsqrtf((float)(dh < 1u ? 1u : dh));
    ri[n0] = rsqrtf((float)(runl < 1u ? 1u : runl));
    ri[n1] = rsqrtf((float)(runh < 1u ? 1u : runh));
}

// ---------------- scan (exclusive prefix over din counts -> CSR offsets) ----------------
__global__ __launch_bounds__(256) void scanA(const int* __restrict__ cnt, int* __restrict__ blks) {
    __shared__ int s[256];
    int t = threadIdx.x;
    int i0 = blockIdx.x * 1024 + t * 4;
    int ts = cnt[i0] + cnt[i0 + 1] + cnt[i0 + 2] + cnt[i0 + 3];
    s[t] = ts; __syncthreads();
    for (int d = 128; d > 0; d >>= 1) { if (t < d) s[t] += s[t + d]; __syncthreads(); }
    if (t == 0) blks[blockIdx.x] = s[0];
}

__global__ __launch_bounds__(256) void scanB(int* __restrict__ blks, int* __restrict__ offN) {
    __shared__ int s[256];
    int t = threadIdx.x;
    int v = blks[t]; s[t] = v; __syncthreads();
    for (int d = 1; d < 256; d <<= 1) {
        int x = (t >= d) ? s[t - d] : 0; __syncthreads();
        s[t] += x; __syncthreads();
    }
    blks[t] = s[t] - v;            // exclusive
    if (t == 255) *offN = s[255];  // total = EE
}

__global__ __launch_bounds__(256) void scanC(const int* __restrict__ cnt, const int* __restrict__ blkoff,
                                             int* __restrict__ off) {
    __shared__ int s[256];
    int t = threadIdx.x;
    int i0 = blockIdx.x * 1024 + t * 4;
    int v0 = cnt[i0], v1 = cnt[i0 + 1], v2 = cnt[i0 + 2], v3 = cnt[i0 + 3];
    int ts = v0 + v1 + v2 + v3;
    s[t] = ts; __syncthreads();
    for (int d = 1; d < 256; d <<= 1) {
        int x = (t >= d) ? s[t - d] : 0; __syncthreads();
        s[t] += x; __syncthreads();
    }
    int base = blkoff[blockIdx.x] + (s[t] - ts);
    off[i0] = base; off[i0 + 1] = base + v0; off[i0 + 2] = base + v0 + v1; off[i0 + 3] = base + v0 + v1 + v2;
}

// ---------------- fill CSR: atomic-free scatter via (slice, rank) + repbase ----------------
__global__ __launch_bounds__(256) void fill_csr(const int* __restrict__ src, const int* __restrict__ dst,
                                                const float* __restrict__ ew, const float* __restrict__ ro,
                                                const int* __restrict__ off,
                                                const unsigned short* __restrict__ repbase16,  // [NSL][NN]
                                                const unsigned short* __restrict__ rankpack16,
                                                int2* __restrict__ edg) {
    int e = blockIdx.x * 256 + threadIdx.x;
    int d = dst[e];
    int s = src[e];
    unsigned pk = rankpack16[e];
    int S = pk >> 10, rank = pk & 1023;
    int p = off[d] + (int)repbase16[(size_t)S * NN + d] + rank;
    edg[p] = make_int2(s, __builtin_bit_cast(int, ew[e] * ro[s]));
}

// ---------------- x fp32 -> bf16 ----------------
__global__ __launch_bounds__(256) void cvt_x(const float* __restrict__ X, short* __restrict__ Xb) {
    int i = (blockIdx.x * 256 + threadIdx.x) * 4;
    float4 v = *(const float4*)(X + i);
    s16x4 o = { f2bf(v.x), f2bf(v.y), f2bf(v.z), f2bf(v.w) };
    *(s16x4*)(Xb + i) = o;
}

// ---------------- gather 64 dims, wave-per-node, edge-parallel 8 edges x 8 chunks of 8 dims ----------------
__global__ __launch_bounds__(256) void gather64(const short* __restrict__ Xb, const int* __restrict__ offs,
                                                const int2* __restrict__ edg, short* __restrict__ Out) {
    const int lane = threadIdx.x & 63;
    const int e = lane >> 3, c = lane & 7;
    int node = blockIdx.x * 4 + (threadIdx.x >> 6);
    node = __builtin_amdgcn_readfirstlane(node);
    const int s0 = offs[node], s1 = offs[node + 1];
    float acc[8] = {};
    for (int j0 = s0; j0 < s1; j0 += 8) {
        int j = j0 + e;
        bool ok = j < s1;
        int2 pe = edg[ok ? j : s0];
        int s = pe.x;
        float w = ok ? __builtin_bit_cast(float, pe.y) : 0.f;
        s16x8 v = *(const s16x8*)&Xb[(size_t)s * 64 + c * 8];
#pragma unroll
        for (int k = 0; k < 8; k++) acc[k] = fmaf(w, bf2f(v[k]), acc[k]);
    }
#pragma unroll
    for (int off = 8; off <= 32; off <<= 1)
#pragma unroll
        for (int k = 0; k < 8; k++) acc[k] += __shfl_xor(acc[k], off);
    if (e == 0) {
        s16x8 o;
#pragma unroll
        for (int k = 0; k < 8; k++) o[k] = f2bf(acc[k]);
        *(s16x8*)&Out[(size_t)node * 64 + c * 8] = o;
    }
}

// ---------------- gather 96 dims, wave-per-node, edge-parallel 8 edges x 8 chunks of 12 dims ----------------
// v2: 8 edges per j-iteration (avg degree 8 -> typically ONE iteration; was 2 with 4-edge groups).
// Same bytes and dword count per row; reduce over e-groups now offs {8,16,32}.
__global__ __launch_bounds__(256) void gather96(const short* __restrict__ H, const int* __restrict__ offs,
                                                const int2* __restrict__ edg, short* __restrict__ Out) {
    const int lane = threadIdx.x & 63;
    const int e = lane >> 3, c = lane & 7;
    int node = blockIdx.x * 4 + (threadIdx.x >> 6);
    node = __builtin_amdgcn_readfirstlane(node);
    const int s0 = offs[node], s1 = offs[node + 1];
    float acc[12] = {};
    for (int j0 = s0; j0 < s1; j0 += 8) {
        int j = j0 + e;
        bool ok = j < s1;
        int2 pe = edg[ok ? j : s0];
        int s = pe.x;
        float w = ok ? __builtin_bit_cast(float, pe.y) : 0.f;
        const unsigned int* hp = (const unsigned int*)(H + (size_t)s * 96 + c * 12);
#pragma unroll
        for (int q = 0; q < 6; q++) {
            unsigned int u = hp[q];
            acc[2 * q]     = fmaf(w, bf2f((short)(u & 0xffff)), acc[2 * q]);
            acc[2 * q + 1] = fmaf(w, bf2f((short)(u >> 16)), acc[2 * q + 1]);
        }
    }
#pragma unroll
    for (int off = 8; off <= 32; off <<= 1)
#pragma unroll
        for (int k = 0; k < 12; k++) acc[k] += __shfl_xor(acc[k], off);
    if (e == 0) {
        unsigned int* op = (unsigned int*)(Out + (size_t)node * 96 + c * 12);
#pragma unroll
        for (int q = 0; q < 6; q++)
            op[q] = (unsigned short)f2bf(acc[2 * q]) | ((unsigned)(unsigned short)f2bf(acc[2 * q + 1]) << 16);
    }
}

// ---------------- fused rsqrt(deg_in)*leaky_relu + GraphNorm (per 64-node graph), bf16 in place ----------------
template <int C>
__global__ __launch_bounds__(256) void graphnorm_k(short* __restrict__ Ag, const float* __restrict__ ri,
                                                   const float* __restrict__ alpha, const float* __restrict__ gamma,
                                                   const float* __restrict__ beta) {
    __shared__ float sm[64 * C];
    __shared__ float sscale[C], sshift[C];
    const int g = blockIdx.x;
    const size_t base = (size_t)g * 64 * C;
    for (int idx = threadIdx.x; idx < 64 * C; idx += 256) {
        int i = idx / C;
        float v = bf2f(Ag[base + idx]) * ri[g * 64 + i];
        sm[idx] = lrelu(v);
    }
    __syncthreads();
    if (threadIdx.x < C) {
        int c = threadIdx.x;
        float s1 = 0.f, s2 = 0.f;
#pragma unroll 4
        for (int i = 0; i < 64; i++) { float v = sm[i * C + c]; s1 += v; s2 += v * v; }
        float m = s1 * (1.f / 64.f);
        float a = alpha[c];
        float var = s2 * (1.f / 64.f) - m * m * a * (2.f - a);   // E[(v-am)^2]
        float sc = gamma[c] * rsqrtf(var + 1e-5f);
        sscale[c] = sc;
        sshift[c] = beta[c] - sc * a * m;
    }
    __syncthreads();
    for (int idx = threadIdx.x; idx < 64 * C; idx += 256) {
        int c = idx % C;
        Ag[base + idx] = f2bf(sscale[c] * sm[idx] + sshift[c]);
    }
}

// ---------------- conv1 + GraphNorm1 fused: MFMA 262144x128x64, block = 128 rows = 2 graphs ----------------
__global__ __launch_bounds__(256) void conv1_gn(const short* __restrict__ A, const short* __restrict__ BT,
                                                const float* __restrict__ ri,
                                                const float* __restrict__ alpha, const float* __restrict__ gamma,
                                                const float* __restrict__ beta, short* __restrict__ Outp) {
    __shared__ short As[128][72];
    __shared__ short Bs[128][72];
    __shared__ float sscale[2][128], sshift[2][128];
    const int t = threadIdx.x;
    const int bm = blockIdx.x * 128;
    const int wave = t >> 6, lane = t & 63;
    const int wm = (wave & 1) * 64, wn = (wave >> 1) * 64;
    const int g = wave & 1;
    const int m16 = lane & 15, quad = lane >> 4;
#pragma unroll
    for (int i = 0; i < 4; i++) {
        int idx = t + 256 * i;
        int rr = idx >> 3, kk = (idx & 7) * 8;
        *(s16x8*)&As[rr][kk] = *(const s16x8*)&A[(size_t)(bm + rr) * 64 + kk];
        *(s16x8*)&Bs[rr][kk] = *(const s16x8*)&BT[(size_t)rr * 64 + kk];
    }
    __syncthreads();
    f32x4 acc[4][4] = {};
#pragma unroll
    for (int kc = 0; kc < 2; kc++) {
        s16x8 af[4], bfr[4];
#pragma unroll
        for (int mt = 0; mt < 4; mt++) af[mt] = *(const s16x8*)&As[wm + mt * 16 + m16][kc * 32 + quad * 8];
#pragma unroll
        for (int nt = 0; nt < 4; nt++) bfr[nt] = *(const s16x8*)&Bs[wn + nt * 16 + m16][kc * 32 + quad * 8];
#pragma unroll
        for (int mt = 0; mt < 4; mt++)
#pragma unroll
            for (int nt = 0; nt < 4; nt++)
                acc[mt][nt] = __builtin_amdgcn_mfma_f32_16x16x32_bf16(af[mt], bfr[nt], acc[mt][nt], 0, 0, 0);
    }
#pragma unroll
    for (int mt = 0; mt < 4; mt++)
#pragma unroll
        for (int r4 = 0; r4 < 4; r4++) {
            float rv = ri[bm + wm + mt * 16 + quad * 4 + r4];
#pragma unroll
            for (int nt = 0; nt < 4; nt++)
                acc[mt][nt][r4] = lrelu(acc[mt][nt][r4] * rv);
        }
#pragma unroll
    for (int nt = 0; nt < 4; nt++) {
        float s1 = 0.f, s2 = 0.f;
#pragma unroll
        for (int mt = 0; mt < 4; mt++)
#pragma unroll
            for (int r4 = 0; r4 < 4; r4++) { float v = acc[mt][nt][r4]; s1 += v; s2 += v * v; }
        s1 += __shfl_xor(s1, 16); s1 += __shfl_xor(s1, 32);
        s2 += __shfl_xor(s2, 16); s2 += __shfl_xor(s2, 32);
        if (quad == 0) {
            int ch = wn + nt * 16 + m16;
            float m = s1 * (1.f / 64.f);
            float a = alpha[ch];
            float var = s2 * (1.f / 64.f) - m * m * a * (2.f - a);   // E[(v-am)^2]
            float sc = gamma[ch] * rsqrtf(var + 1e-5f);
            sscale[g][ch] = sc;
            sshift[g][ch] = beta[ch] - sc * a * m;
        }
    }
    __syncthreads();
#pragma unroll
    for (int nt = 0; nt < 4; nt++) {
        int ch = wn + nt * 16 + m16;
        float sc = sscale[g][ch], sh = sshift[g][ch];
#pragma unroll
        for (int mt = 0; mt < 4; mt++)
#pragma unroll
            for (int r4 = 0; r4 < 4; r4++) {
                int row = bm + wm + mt * 16 + quad * 4 + r4;
                Outp[(size_t)row * 128 + ch] = f2bf(sc * acc[mt][nt][r4] + sh);
            }
    }
}

// ---------------- conv2: MFMA GEMM 262144x96x128, A=gn1 bf16, BT=W2T bf16 (96x128), out h2 bf16 ----------------
__global__ __launch_bounds__(256) void conv2_mfma(const short* __restrict__ A, const short* __restrict__ BT,
                                                  short* __restrict__ H) {
    __shared__ short As[128][136];   // 128 k + 8 pad
    __shared__ short Bs[96][136];
    const int t = threadIdx.x;
    const int bm = blockIdx.x * 128;
    const int wave = t >> 6, lane = t & 63;
    const int wm = (wave & 1) * 64, wn = (wave >> 1) * 48;
    const int m16 = lane & 15, quad = lane >> 4;
#pragma unroll
    for (int i = 0; i < 8; i++) {
        int idx = t + 256 * i;
        int rr = idx >> 4, kk = (idx & 15) * 8;
        *(s16x8*)&As[rr][kk] = *(const s16x8*)&A[(size_t)(bm + rr) * 128 + kk];
    }
#pragma unroll
    for (int i = 0; i < 6; i++) {
        int idx = t + 256 * i;
        int nr = idx >> 4, kk = (idx & 15) * 8;
        *(s16x8*)&Bs[nr][kk] = *(const s16x8*)&BT[(size_t)nr * 128 + kk];
    }
    __syncthreads();
    f32x4 acc[4][3] = {};
#pragma unroll
    for (int kc = 0; kc < 4; kc++) {
        s16x8 af[4], bfr[3];
#pragma unroll
        for (int mt = 0; mt < 4; mt++) af[mt] = *(const s16x8*)&As[wm + mt * 16 + m16][kc * 32 + quad * 8];
#pragma unroll
        for (int nt = 0; nt < 3; nt++) bfr[nt] = *(const s16x8*)&Bs[wn + nt * 16 + m16][kc * 32 + quad * 8];
#pragma unroll
        for (int mt = 0; mt < 4; mt++)
#pragma unroll
            for (int nt = 0; nt < 3; nt++)
                acc[mt][nt] = __builtin_amdgcn_mfma_f32_16x16x32_bf16(af[mt], bfr[nt], acc[mt][nt], 0, 0, 0);
    }
#pragma unroll
    for (int mt = 0; mt < 4; mt++)
#pragma unroll
        for (int r4 = 0; r4 < 4; r4++) {
            int row = bm + wm + mt * 16 + quad * 4 + r4;
#pragma unroll
            for (int nt = 0; nt < 3; nt++)
                H[(size_t)row * 96 + wn + nt * 16 + m16] = f2bf(acc[mt][nt][r4]);
        }
}

// ---------------- W fp32 (R x Cc) -> WT bf16 (Cc x R), tiled transpose+convert ----------------
__global__ __launch_bounds__(256) void transp_cvt(const float* __restrict__ W, short* __restrict__ WT,
                                                  int R, int Cc) {
    __shared__ short tile[32][33];
    const int bc = blockIdx.x * 32;   // col of W
    const int br = blockIdx.y * 32;   // row of W
    const int tx = threadIdx.x & 31, ty = threadIdx.x >> 5;   // 32 x 8
#pragma unroll
    for (int i = 0; i < 32; i += 8)
        tile[ty + i][tx] = f2bf(W[(size_t)(br + ty + i) * Cc + bc + tx]);
    __syncthreads();
#pragma unroll
    for (int i = 0; i < 32; i += 8)
        WT[(size_t)(bc + ty + i) * R + br + tx] = tile[tx][ty + i];
}

// ---------------- MLP1: 256x256-tile 8-phase split-K bf16 MFMA GEMM (round-2 verified, 129 us) ----------------
#define MBAR() __builtin_amdgcn_s_barrier()
#define LGKM0() asm volatile("s_waitcnt lgkmcnt(0)" ::: "memory")
#define SB0() __builtin_amdgcn_sched_barrier(0)
#define VMC4() asm volatile("s_waitcnt vmcnt(4)" ::: "memory")
#define VMC2() asm volatile("s_waitcnt vmcnt(2)" ::: "memory")
#define VMC0() asm volatile("s_waitcnt vmcnt(0)" ::: "memory")

__global__ __launch_bounds__(512, 2) void mlp1_mfma8(const short* __restrict__ A, const short* __restrict__ BT,
                                                     short* __restrict__ Cp) {
    constexpr int K = INMLP;
    __shared__ short As[2][256 * 64];
    __shared__ short Bs[2][256 * 64];
    const int t = threadIdx.x;
    const int wid = t >> 6, lane = t & 63;
    const int lrow = lane >> 3, lcol = lane & 7;
    const int scol = lcol ^ (lrow & 7);
    const int m16 = lane & 15, quad = lane >> 4, xkey = m16 & 7;
    const int wm = wid & 1, wn = wid >> 1;
    const int sw = (blockIdx.x & 7) * 32 + (blockIdx.x >> 3);
    const int bm = sw & 15, bn = (sw >> 4) & 7, z = sw >> 7;
    const short* gA = A + (size_t)(bm * 256 + lrow) * K + (size_t)z * (K / 2) + scol * 8;
    const short* gB = BT + (size_t)(bn * 256 + lrow) * K + (size_t)z * (K / 2) + scol * 8;

    f32x4 acc[8][4] = {};

#define STG(gp, Xs, s, r0, ko) \
    async16(gp + (size_t)((r0) + wid * 8) * K + (ko), &Xs[s][((r0) + wid * 8) * 64])
#define STAGE_B4(s, ko) { STG(gB, Bs, s, 0, ko); STG(gB, Bs, s, 64, ko); STG(gB, Bs, s, 128, ko); STG(gB, Bs, s, 192, ko); }
#define STAGE_A4(s, ko) { STG(gA, As, s, 0, ko); STG(gA, As, s, 128, ko); STG(gA, As, s, 64, ko); STG(gA, As, s, 192, ko); }
#define PH_LOAD(s, kc, mh) \
    { _Pragma("unroll") for (int mt = 0; mt < 4; mt++) \
          af[mt] = *(const s16x8*)&As[s][(wm * 128 + (mh) * 64 + mt * 16 + m16) * 64 + (((kc) * 4 + quad) ^ xkey) * 8]; \
      _Pragma("unroll") for (int nt = 0; nt < 4; nt++) \
          bfr[nt] = *(const s16x8*)&Bs[s][(wn * 64 + nt * 16 + m16) * 64 + (((kc) * 4 + quad) ^ xkey) * 8]; }
#define PH_MM(mh) \
    { _Pragma("unroll") for (int mt = 0; mt < 4; mt++) \
          _Pragma("unroll") for (int nt = 0; nt < 4; nt++) \
              acc[(mh) * 4 + mt][nt] = __builtin_amdgcn_mfma_f32_16x16x32_bf16(af[mt], bfr[nt], acc[(mh) * 4 + mt][nt], 0, 0, 0); }

    STAGE_B4(0, 0); STAGE_A4(0, 0);
    VMC2();
    MBAR();

    int kof = 0;
#pragma unroll 1
    for (int i = 0; i < 24; i++, kof += 128) {
        const bool st = (i < 23);
        s16x8 af[4], bfr[4];
        // ph1
        PH_LOAD(0, 0, 0); STAGE_B4(1, kof + 64);
        MBAR(); LGKM0(); SB0();
        __builtin_amdgcn_s_setprio(1); PH_MM(0); __builtin_amdgcn_s_setprio(0);
        VMC4(); MBAR();
        // ph2
        PH_LOAD(0, 0, 1); STAGE_A4(1, kof + 64);
        MBAR(); LGKM0(); SB0();
        __builtin_amdgcn_s_setprio(1); PH_MM(1); __builtin_amdgcn_s_setprio(0);
        MBAR();
        // ph3
        PH_LOAD(0, 1, 0);
        MBAR(); LGKM0(); SB0();
        __builtin_amdgcn_s_setprio(1); PH_MM(0); __builtin_amdgcn_s_setprio(0);
        MBAR();
        // ph4
        PH_LOAD(0, 1, 1);
        MBAR(); LGKM0(); SB0();
        __builtin_amdgcn_s_setprio(1); PH_MM(1); __builtin_amdgcn_s_setprio(0);
        VMC2(); MBAR();
        // ph5
        PH_LOAD(1, 0, 0);
        if (st) STAGE_B4(0, kof + 128);
        MBAR(); LGKM0(); SB0();
        __builtin_amdgcn_s_setprio(1); PH_MM(0); __builtin_amdgcn_s_setprio(0);
        if (st) { VMC4(); } else { VMC0(); }
        MBAR();
        // ph6
        PH_LOAD(1, 0, 1);
        if (st) STAGE_A4(0, kof + 128);
        MBAR(); LGKM0(); SB0();
        __builtin_amdgcn_s_setprio(1); PH_MM(1); __builtin_amdgcn_s_setprio(0);
        MBAR();
        // ph7
        PH_LOAD(1, 1, 0);
        MBAR(); LGKM0(); SB0();
        __builtin_amdgcn_s_setprio(1); PH_MM(0); __builtin_amdgcn_s_setprio(0);
        MBAR();
        // ph8
        PH_LOAD(1, 1, 1);
        MBAR(); LGKM0(); SB0();
        __builtin_amdgcn_s_setprio(1); PH_MM(1); __builtin_amdgcn_s_setprio(0);
        if (st) { VMC2(); }
        MBAR();
    }

    short* C = Cp + (size_t)z * BB * HID;
    const int r0 = bm * 256 + wm * 128 + quad * 4;
    const int c0 = bn * 256 + wn * 64 + m16;
#pragma unroll
    for (int mt = 0; mt < 8; mt++)
#pragma unroll
        for (int nt = 0; nt < 4; nt++)
#pragma unroll
            for (int r4 = 0; r4 < 4; r4++)
                C[(size_t)(r0 + mt * 16 + r4) * HID + c0 + nt * 16] = f2bf(acc[mt][nt][r4]);
#undef STG
#undef STAGE_A4
#undef STAGE_B4
#undef PH_LOAD
#undef PH_MM
}

// ---------------- combine split-K partials + leaky + InstanceNorm, bf16 in place (D0) ----------------
__global__ __launch_bounds__(256) void rownorm_hid(short* __restrict__ D0, const short* __restrict__ D1) {
    const size_t base = (size_t)blockIdx.x * HID;
    float v[8];
    float s1 = 0.f, s2 = 0.f;
    const int c0 = threadIdx.x * 8;
    {
        s16x8 a = *(const s16x8*)&D0[base + c0];
        s16x8 b = *(const s16x8*)&D1[base + c0];
#pragma unroll
        for (int k = 0; k < 8; k++) {
            float x = lrelu(bf2f(a[k]) + bf2f(b[k]));
            v[k] = x; s1 += x; s2 += x * x;
        }
    }
#pragma unroll
    for (int o = 32; o > 0; o >>= 1) { s1 += __shfl_down(s1, o); s2 += __shfl_down(s2, o); }
    __shared__ float w1[4], w2[4];
    if ((threadIdx.x & 63) == 0) { w1[threadIdx.x >> 6] = s1; w2[threadIdx.x >> 6] = s2; }
    __syncthreads();
    s1 = w1[0] + w1[1] + w1[2] + w1[3];
    s2 = w2[0] + w2[1] + w2[2] + w2[3];
    float m = s1 * (1.f / HID);
    float inv = rsqrtf(s2 * (1.f / HID) - m * m + 1e-5f);
    s16x8 o;
#pragma unroll
    for (int k = 0; k < 8; k++) o[k] = f2bf((v[k] - m) * inv);
    *(s16x8*)&D0[base + c0] = o;
}

// ---------------- generic MFMA GEMM: A bf16 or fp32 (converted on stage), BT bf16, C fp32 ----------------
template <bool ABF16, bool LEAKY>
__global__ __launch_bounds__(256) void mfma_gemm(const float* __restrict__ Af, const short* __restrict__ Ab,
                                                 const short* __restrict__ BT,
                                                 float* __restrict__ C, int M, int Nn, int K) {
    __shared__ short As[64][40];
    __shared__ short Bs[64][40];
    const int t = threadIdx.x;
    const int bm = blockIdx.x * 64, bn = blockIdx.y * 64;
    const int wave = t >> 6, lane = t & 63;
    const int wm = (wave & 1) * 32, wn = (wave >> 1) * 32;
    const int m16 = lane & 15, quad = lane >> 4;
    const int rr = t >> 2, kk = (t & 3) * 8;
    f32x4 acc[2][2] = {};
    for (int k0 = 0; k0 < K; k0 += 32) {
        if (ABF16) {
            *(s16x8*)&As[rr][kk] = *(const s16x8*)&Ab[(size_t)(bm + rr) * K + k0 + kk];
        } else {
            const float* ap = &Af[(size_t)(bm + rr) * K + k0 + kk];
            float4 v0 = *(const float4*)ap;
            float4 v1 = *(const float4*)(ap + 4);
            s16x8 a8;
            a8[0] = f2bf(v0.x); a8[1] = f2bf(v0.y); a8[2] = f2bf(v0.z); a8[3] = f2bf(v0.w);
            a8[4] = f2bf(v1.x); a8[5] = f2bf(v1.y); a8[6] = f2bf(v1.z); a8[7] = f2bf(v1.w);
            *(s16x8*)&As[rr][kk] = a8;
        }
        *(s16x8*)&Bs[rr][kk] = *(const s16x8*)&BT[(size_t)(bn + rr) * K + k0 + kk];
        __syncthreads();
        s16x8 af[2], bfr[2];
#pragma unroll
        for (int mt = 0; mt < 2; mt++) af[mt] = *(const s16x8*)&As[wm + mt * 16 + m16][quad * 8];
#pragma unroll
        for (int nt = 0; nt < 2; nt++) bfr[nt] = *(const s16x8*)&Bs[wn + nt * 16 + m16][quad * 8];
#pragma unroll
        for (int mt = 0; mt < 2; mt++)
#pragma unroll
            for (int nt = 0; nt < 2; nt++)
                acc[mt][nt] = __builtin_amdgcn_mfma_f32_16x16x32_bf16(af[mt], bfr[nt], acc[mt][nt], 0, 0, 0);
        __syncthreads();
    }
#pragma unroll
    for (int mt = 0; mt < 2; mt++)
#pragma unroll
        for (int nt = 0; nt < 2; nt++)
#pragma unroll
            for (int r4 = 0; r4 < 4; r4++) {
                int row = bm + wm + mt * 16 + quad * 4 + r4;
                int col = bn + wn + nt * 16 + m16;
                float v = acc[mt][nt][r4];
                if (LEAKY) v = lrelu(v);
                C[(size_t)row * Nn + col] = v;
            }
}

// ---------------- per-row InstanceNorm (in place, fp32) ----------------
template <int NC>
__global__ __launch_bounds__(256) void rownorm(float* __restrict__ Y) {
    float* p = Y + (size_t)blockIdx.x * NC;
    float s1 = 0.f, s2 = 0.f;
    for (int c = threadIdx.x; c < NC; c += 256) { float v = p[c]; s1 += v; s2 += v * v; }
#pragma unroll
    for (int o = 32; o > 0; o >>= 1) { s1 += __shfl_down(s1, o); s2 += __shfl_down(s2, o); }
    __shared__ float w1[4], w2[4];
    if ((threadIdx.x & 63) == 0) { w1[threadIdx.x >> 6] = s1; w2[threadIdx.x >> 6] = s2; }
    __syncthreads();
    s1 = w1[0] + w1[1] + w1[2] + w1[3];
    s2 = w2[0] + w2[1] + w2[2] + w2[3];
    float m = s1 * (1.f / NC);
    float inv = rsqrtf(s2 * (1.f / NC) - m * m + 1e-5f);
    for (int c = threadIdx.x; c < NC; c += 256) p[c] = (p[c] - m) * inv;
}

extern "C" void kernel_launch(void* const* d_in, const int* in_sizes, int n_in,
                              void* d_out, int out_size, void* d_ws, size_t ws_size,
                              hipStream_t stream) {
    const float* x    = (const float*)d_in[0];
    const float* ew   = (const float*)d_in[1];
    const int*   src  = (const int*)d_in[2];
    const int*   dst  = (const int*)d_in[3];
    const float* W1   = (const float*)d_in[4];
    const float* W2   = (const float*)d_in[5];
    const float* a1   = (const float*)d_in[6];
    const float* g1   = (const float*)d_in[7];
    const float* b1   = (const float*)d_in[8];
    const float* a2   = (const float*)d_in[9];
    const float* g2   = (const float*)d_in[10];
    const float* b2   = (const float*)d_in[11];
    const float* Win  = (const float*)d_in[12];
    const float* Whid = (const float*)d_in[13];
    const float* Wcls = (const float*)d_in[14];
    float* out = (float*)d_out;

    // ---- workspace layout ----
    float* ro   = (float*)d_ws;                    // NN
    float* ri   = ro + NN;                         // NN
    int*   din  = (int*)(ri + NN);                 // NN (deg_in for scan)
    int*   offs = din + NN;                        // NN+4
    int*   blks = offs + NN + 4;                   // 256
    short* w1t  = (short*)(blks + 256);            // 128*64 bf16
    short* w2t  = w1t + 128 * 64;                  // 96*128 bf16
    int2*  edg  = (int2*)(((size_t)(w2t + 96 * 128) + 15) & ~(size_t)15);   // EE int2 (src, ew*ro), 16.8 MB
    short* Abf  = (short*)(edg + EE);              // 64 MiB region
    short* Bbf  = Abf + (size_t)NN * 128;          // 64 MiB region
    short* xbf  = Abf;                             // NN*64
    short* aggx = Abf + (size_t)NN * 64;           // NN*64
    // graph-build temps: part arrays fill Abf; repbase+rank in Bbf
    unsigned*       part_din   = (unsigned*)Abf;                       // NSL * NN/2 words (32 MiB)
    unsigned*       part_dout  = part_din + (size_t)NSL * (NN / 2);    // 32 MiB
    unsigned*       repbase_w  = (unsigned*)Bbf;                       // 32 MiB
    unsigned short* rankpack16 = (unsigned short*)(repbase_w + (size_t)NSL * (NN / 2));  // EE u16
    // overlays into Abf region after gather96 (h2 dead):
    short* WinT = Abf;                                      // 2048*6144 bf16 = 25165824 B
    short* D0   = (short*)((char*)Abf + 25165824);          // 4096*2048 bf16 = 16777216 B
    short* D1   = D0 + (size_t)BB * HID;                    // 4096*2048 bf16 = 16777216 B  (total 58.7 MB <= 64 MiB)
    // Y2 in edg region (edg dead after gather96):
    float* Y2   = (float*)edg;                              // 4096*512 fp32 = 8388608 B <= 16.8 MB
    // overlays into Bbf region after mlp1_mfma8 consumes gn2:
    short* WhidT = Bbf;                            // 512*2048 bf16
    short* WclsT = WhidT + (size_t)HID4 * HID;     // 256*512 bf16

    // 1) degrees + per-edge ranks via LDS histograms (1024 blocks, int4 streaming)
    hist_count<<<2 * 8 * NSL, 256, 0, stream>>>(dst, src, part_din, part_dout, rankpack16);
    deg_reduce<<<NN / 512, 256, 0, stream>>>(part_din, part_dout, repbase_w, ro, ri, din);

    // 2) CSR by dst: scan + atomic-free fill
    scanA<<<NN / 1024, 256, 0, stream>>>(din, blks);
    scanB<<<1, 256, 0, stream>>>(blks, offs + NN);
    scanC<<<NN / 1024, 256, 0, stream>>>(din, blks, offs);
    fill_csr<<<EE / 256, 256, 0, stream>>>(src, dst, ew, ro, offs,
                                           (const unsigned short*)repbase_w, rankpack16, edg);

    // 3) conv layer 1: gather x (64 dims), then GEMM + fused GraphNorm1
    cvt_x<<<NN * 64 / 1024, 256, 0, stream>>>(x, xbf);
    transp_cvt<<<dim3(128 / 32, 64 / 32), 256, 0, stream>>>(W1, w1t, 64, 128);
    gather64<<<NN / 4, 256, 0, stream>>>(xbf, offs, edg, aggx);
    conv1_gn<<<NN / 128, 256, 0, stream>>>(aggx, w1t, ri, a1, g1, b1, Bbf);   // Bbf = gn1

    // 4) conv layer 2: GEMM, then wave-per-node gather, then GraphNorm2
    transp_cvt<<<dim3(96 / 32, 128 / 32), 256, 0, stream>>>(W2, w2t, 128, 96);
    conv2_mfma<<<NN / 128, 256, 0, stream>>>(Bbf, w2t, Abf);                  // h2 (xbf/aggx dead)
    gather96<<<NN / 4, 256, 0, stream>>>(Abf, offs, edg, Bbf);                // Bbf = agg2 (gn1 dead)
    graphnorm_k<96><<<BB, 256, 0, stream>>>(Bbf, ri, a2, g2, b2);             // Bbf = gn2 (MLP input)

    // 5) MLP
    transp_cvt<<<dim3(HID / 32, INMLP / 32), 256, 0, stream>>>(Win, WinT, INMLP, HID);
    mlp1_mfma8<<<256, 512, 0, stream>>>(Bbf, WinT, D0);                       // 8-phase split-K partials
    transp_cvt<<<dim3(HID4 / 32, HID / 32), 256, 0, stream>>>(Whid, WhidT, HID, HID4);
    transp_cvt<<<dim3(OUTF / 32, HID4 / 32), 256, 0, stream>>>(Wcls, WclsT, HID4, OUTF);
    rownorm_hid<<<BB, 256, 0, stream>>>(D0, D1);                                  // D0 = norm(lrelu(D0+D1)) bf16
    mfma_gemm<true, true><<<dim3(BB / 64, HID4 / 64), 256, 0, stream>>>(nullptr, D0, WhidT, Y2, BB, HID4, HID);
    rownorm<HID4><<<BB, 256, 0, stream>>>(Y2);
    mfma_gemm<false, false><<<dim3(BB / 64, OUTF / 64), 256, 0, stream>>>(Y2, nullptr, WclsT, out, BB, OUTF, HID4);
}

// Round 7
// 768.994 us; speedup vs baseline: 1.1806x; 1.0488x over previous
//
#include <hip/hip_runtime.h>
#include <hip/hip_bf16.h>

// Problem constants (fixed-shape problem)
#define NN 262144      // nodes = 4096 graphs * 64
#define EE 2097152     // edges
#define BB 4096        // graphs
constexpr int INMLP = 6144;
constexpr int HID = 2048;
constexpr int HID4 = 512;
constexpr int OUTF = 256;
constexpr int NSL = 64;            // edge slices
constexpr int ESL = EE / NSL;      // 32768 edges per slice
constexpr int RN4 = 65536;         // nodes per range (4 ranges, u8 counters in 64 KB LDS)

typedef short s16x8 __attribute__((ext_vector_type(8)));   // 8 bf16 in 4 VGPRs
typedef short s16x4 __attribute__((ext_vector_type(4)));
typedef float f32x4 __attribute__((ext_vector_type(4)));

__device__ __forceinline__ float lrelu(float v) { return v >= 0.f ? v : 0.01f * v; }
__device__ __forceinline__ float bf2f(short s) {
    unsigned int u = ((unsigned int)(unsigned short)s) << 16;
    return __builtin_bit_cast(float, u);
}
__device__ __forceinline__ short f2bf(float f) {   // RNE
    unsigned int u = __builtin_bit_cast(unsigned int, f);
    u = (u + 0x7fff + ((u >> 16) & 1)) >> 16;
    return (short)u;
}
// async global->LDS, 16B per lane. LDS dest = wave-uniform base + lane*16.
__device__ __forceinline__ void async16(const void* g, void* l) {
    __builtin_amdgcn_global_load_lds((__attribute__((address_space(1))) void*)g,
                                     (__attribute__((address_space(3))) void*)l, 16, 0, 0);
}

// ---------------- degree counting via LDS u8 histograms (4 ranges, 2 types = 8 passes) ----------------
// u8 per-(slice,node) counters: per-slice per-node count <= ~30 << 255, so 65536 nodes fit 64 KB LDS
// -> halves edge-stream passes vs u16/8-range (64 MB vs 128 MB) and halves partial traffic.
__global__ __launch_bounds__(256) void hist_count(const int* __restrict__ dst, const int* __restrict__ src,
                                                  unsigned* __restrict__ part_din, unsigned* __restrict__ part_dout,
                                                  unsigned short* __restrict__ rankpack16) {
    __shared__ unsigned hist[RN4 / 4];   // 65536 B (u8 lanes in u32)
    const int S = blockIdx.x & 63;
    const int R = (blockIdx.x >> 6) & 3;
    const int T = blockIdx.x >> 8;          // 0 = din(dst)+rank, 1 = dout(src)
    for (int i = threadIdx.x; i < RN4 / 4; i += 256) hist[i] = 0;
    __syncthreads();
    const int* idxarr = T ? src : dst;
    const int4* v4 = (const int4*)(idxarr + S * ESL);
#pragma unroll 4
    for (int i = 0; i < ESL / 4 / 256; i++) {            // 32 iterations
        const int q0 = i * 256 + threadIdx.x;
        int4 q = v4[q0];
        const int ebase = S * ESL + q0 * 4;
#pragma unroll
        for (int k = 0; k < 4; k++) {
            int idx = k == 0 ? q.x : k == 1 ? q.y : k == 2 ? q.z : q.w;
            if ((idx >> 16) == R) {
                int local = idx & (RN4 - 1);
                unsigned old = atomicAdd(&hist[local >> 2], 1u << ((local & 3) * 8));
                if (T == 0) {
                    unsigned rank = (old >> ((local & 3) * 8)) & 0xffu;
                    rankpack16[ebase + k] = (unsigned short)((S << 10) | rank);   // rank <= 255 < 1024
                }
            }
        }
    }
    __syncthreads();
    unsigned* dp = (T ? part_dout : part_din) + (size_t)S * (NN / 4) + R * (RN4 / 4);
    for (int i = threadIdx.x; i < RN4 / 4; i += 256) dp[i] = hist[i];
}

// ---------------- reduce slices: degrees, rsqrt factors, per-(slice,node) base offsets ----------------
// part arrays are u8-packed [NSL][NN/4 words]; repbase stays u16-packed [NSL][NN/2 words] (fill_csr ABI).
__global__ __launch_bounds__(256) void deg_reduce(const unsigned* __restrict__ part_din,
                                                  const unsigned* __restrict__ part_dout,
                                                  unsigned* __restrict__ repbase_w,   // [NSL][NN/2] packed u16
                                                  float* __restrict__ ro, float* __restrict__ ri,
                                                  int* __restrict__ din) {
    int i = blockIdx.x * 256 + threadIdx.x;    // u8-word index over NN/4
    unsigned r0 = 0, r1 = 0, r2 = 0, r3 = 0, d0 = 0, d1 = 0, d2 = 0, d3 = 0;
#pragma unroll 8
    for (int S = 0; S < NSL; S++) {
        repbase_w[(size_t)S * (NN / 2) + 2 * i]     = (r0 & 0xffffu) | ((r1 & 0xffffu) << 16);
        repbase_w[(size_t)S * (NN / 2) + 2 * i + 1] = (r2 & 0xffffu) | ((r3 & 0xffffu) << 16);
        unsigned w = part_din[(size_t)S * (NN / 4) + i];
        r0 += w & 0xffu; r1 += (w >> 8) & 0xffu; r2 += (w >> 16) & 0xffu; r3 += w >> 24;
        unsigned w2 = part_dout[(size_t)S * (NN / 4) + i];
        d0 += w2 & 0xffu; d1 += (w2 >> 8) & 0xffu; d2 += (w2 >> 16) & 0xffu; d3 += w2 >> 24;
    }
    int n = 4 * i;
    *(int4*)&din[n] = make_int4((int)r0, (int)r1, (int)r2, (int)r3);
    float4 vo, vi;
    vo.x = rsqrtf((float)(d0 < 1u ? 1u : d0)); vo.y = rsqrtf((float)(d1 < 1u ? 1u : d1));
    vo.z = rsqrtf((float)(d2 < 1u ? 1u : d2)); vo.w = rsqrtf((float)(d3 < 1u ? 1u : d3));
    vi.x = rsqrtf((float)(r0 < 1u ? 1u : r0)); vi.y = rsqrtf((float)(r1 < 1u ? 1u : r1));
    vi.z = rsqrtf((float)(r2 < 1u ? 1u : r2)); vi.w = rsqrtf((float)(r3 < 1u ? 1u : r3));
    *(float4*)&ro[n] = vo;
    *(float4*)&ri[n] = vi;
}

// ---------------- scan (exclusive prefix over din counts -> CSR offsets) ----------------
__global__ __launch_bounds__(256) void scanA(const int* __restrict__ cnt, int* __restrict__ blks) {
    __shared__ int s[256];
    int t = threadIdx.x;
    int i0 = blockIdx.x * 1024 + t * 4;
    int ts = cnt[i0] + cnt[i0 + 1] + cnt[i0 + 2] + cnt[i0 + 3];
    s[t] = ts; __syncthreads();
    for (int d = 128; d > 0; d >>= 1) { if (t < d) s[t] += s[t + d]; __syncthreads(); }
    if (t == 0) blks[blockIdx.x] = s[0];
}

__global__ __launch_bounds__(256) void scanB(int* __restrict__ blks, int* __restrict__ offN) {
    __shared__ int s[256];
    int t = threadIdx.x;
    int v = blks[t]; s[t] = v; __syncthreads();
    for (int d = 1; d < 256; d <<= 1) {
        int x = (t >= d) ? s[t - d] : 0; __syncthreads();
        s[t] += x; __syncthreads();
    }
    blks[t] = s[t] - v;            // exclusive
    if (t == 255) *offN = s[255];  // total = EE
}

__global__ __launch_bounds__(256) void scanC(const int* __restrict__ cnt, const int* __restrict__ blkoff,
                                             int* __restrict__ off) {
    __shared__ int s[256];
    int t = threadIdx.x;
    int i0 = blockIdx.x * 1024 + t * 4;
    int v0 = cnt[i0], v1 = cnt[i0 + 1], v2 = cnt[i0 + 2], v3 = cnt[i0 + 3];
    int ts = v0 + v1 + v2 + v3;
    s[t] = ts; __syncthreads();
    for (int d = 1; d < 256; d <<= 1) {
        int x = (t >= d) ? s[t - d] : 0; __syncthreads();
        s[t] += x; __syncthreads();
    }
    int base = blkoff[blockIdx.x] + (s[t] - ts);
    off[i0] = base; off[i0 + 1] = base + v0; off[i0 + 2] = base + v0 + v1; off[i0 + 3] = base + v0 + v1 + v2;
}

// ---------------- fill CSR: atomic-free scatter via (slice, rank) + repbase ----------------
__global__ __launch_bounds__(256) void fill_csr(const int* __restrict__ src, const int* __restrict__ dst,
                                                const float* __restrict__ ew, const float* __restrict__ ro,
                                                const int* __restrict__ off,
                                                const unsigned short* __restrict__ repbase16,  // [NSL][NN]
                                                const unsigned short* __restrict__ rankpack16,
                                                int2* __restrict__ edg) {
    int e = blockIdx.x * 256 + threadIdx.x;
    int d = dst[e];
    int s = src[e];
    unsigned pk = rankpack16[e];
    int S = pk >> 10, rank = pk & 1023;
    int p = off[d] + (int)repbase16[(size_t)S * NN + d] + rank;
    edg[p] = make_int2(s, __builtin_bit_cast(int, ew[e] * ro[s]));
}

// ---------------- x fp32 -> bf16 ----------------
__global__ __launch_bounds__(256) void cvt_x(const float* __restrict__ X, short* __restrict__ Xb) {
    int i = (blockIdx.x * 256 + threadIdx.x) * 4;
    float4 v = *(const float4*)(X + i);
    s16x4 o = { f2bf(v.x), f2bf(v.y), f2bf(v.z), f2bf(v.w) };
    *(s16x4*)(Xb + i) = o;
}

// ---------------- gather 64 dims, wave-per-node, edge-parallel 8 edges x 8 chunks of 8 dims ----------------
__global__ __launch_bounds__(256) void gather64(const short* __restrict__ Xb, const int* __restrict__ offs,
                                                const int2* __restrict__ edg, short* __restrict__ Out) {
    const int lane = threadIdx.x & 63;
    const int e = lane >> 3, c = lane & 7;
    int node = blockIdx.x * 4 + (threadIdx.x >> 6);
    node = __builtin_amdgcn_readfirstlane(node);
    const int s0 = offs[node], s1 = offs[node + 1];
    float acc[8] = {};
    for (int j0 = s0; j0 < s1; j0 += 8) {
        int j = j0 + e;
        bool ok = j < s1;
        int2 pe = edg[ok ? j : s0];
        int s = pe.x;
        float w = ok ? __builtin_bit_cast(float, pe.y) : 0.f;
        s16x8 v = *(const s16x8*)&Xb[(size_t)s * 64 + c * 8];
#pragma unroll
        for (int k = 0; k < 8; k++) acc[k] = fmaf(w, bf2f(v[k]), acc[k]);
    }
#pragma unroll
    for (int off = 8; off <= 32; off <<= 1)
#pragma unroll
        for (int k = 0; k < 8; k++) acc[k] += __shfl_xor(acc[k], off);
    if (e == 0) {
        s16x8 o;
#pragma unroll
        for (int k = 0; k < 8; k++) o[k] = f2bf(acc[k]);
        *(s16x8*)&Out[(size_t)node * 64 + c * 8] = o;
    }
}

// ---------------- gather 96 dims, wave-per-node, edge-parallel 4 edges x 16 chunks of 6 dims ----------------
__global__ __launch_bounds__(256) void gather96(const short* __restrict__ H, const int* __restrict__ offs,
                                                const int2* __restrict__ edg, short* __restrict__ Out) {
    const int lane = threadIdx.x & 63;
    const int e = lane >> 4, c = lane & 15;
    int node = blockIdx.x * 4 + (threadIdx.x >> 6);
    node = __builtin_amdgcn_readfirstlane(node);
    const int s0 = offs[node], s1 = offs[node + 1];
    float acc[6] = {};
    for (int j0 = s0; j0 < s1; j0 += 4) {
        int j = j0 + e;
        bool ok = j < s1;
        int2 pe = edg[ok ? j : s0];
        int s = pe.x;
        float w = ok ? __builtin_bit_cast(float, pe.y) : 0.f;
        const unsigned int* hp = (const unsigned int*)(H + (size_t)s * 96 + c * 6);
        unsigned int u0 = hp[0], u1 = hp[1], u2 = hp[2];
        acc[0] = fmaf(w, bf2f((short)(u0 & 0xffff)), acc[0]);
        acc[1] = fmaf(w, bf2f((short)(u0 >> 16)), acc[1]);
        acc[2] = fmaf(w, bf2f((short)(u1 & 0xffff)), acc[2]);
        acc[3] = fmaf(w, bf2f((short)(u1 >> 16)), acc[3]);
        acc[4] = fmaf(w, bf2f((short)(u2 & 0xffff)), acc[4]);
        acc[5] = fmaf(w, bf2f((short)(u2 >> 16)), acc[5]);
    }
#pragma unroll
    for (int off = 16; off <= 32; off <<= 1)
#pragma unroll
        for (int k = 0; k < 6; k++) acc[k] += __shfl_xor(acc[k], off);
    if (e == 0) {
        unsigned int* op = (unsigned int*)(Out + (size_t)node * 96 + c * 6);
        op[0] = (unsigned short)f2bf(acc[0]) | ((unsigned)(unsigned short)f2bf(acc[1]) << 16);
        op[1] = (unsigned short)f2bf(acc[2]) | ((unsigned)(unsigned short)f2bf(acc[3]) << 16);
        op[2] = (unsigned short)f2bf(acc[4]) | ((unsigned)(unsigned short)f2bf(acc[5]) << 16);
    }
}

// ---------------- fused rsqrt(deg_in)*leaky_relu + GraphNorm (per 64-node graph), bf16 in place ----------------
template <int C>
__global__ __launch_bounds__(256) void graphnorm_k(short* __restrict__ Ag, const float* __restrict__ ri,
                                                   const float* __restrict__ alpha, const float* __restrict__ gamma,
                                                   const float* __restrict__ beta) {
    __shared__ float sm[64 * C];
    __shared__ float sscale[C], sshift[C];
    const int g = blockIdx.x;
    const size_t base = (size_t)g * 64 * C;
    for (int idx = threadIdx.x; idx < 64 * C; idx += 256) {
        int i = idx / C;
        float v = bf2f(Ag[base + idx]) * ri[g * 64 + i];
        sm[idx] = lrelu(v);
    }
    __syncthreads();
    if (threadIdx.x < C) {
        int c = threadIdx.x;
        float s1 = 0.f, s2 = 0.f;
#pragma unroll 4
        for (int i = 0; i < 64; i++) { float v = sm[i * C + c]; s1 += v; s2 += v * v; }
        float m = s1 * (1.f / 64.f);
        float a = alpha[c];
        float var = s2 * (1.f / 64.f) - m * m * a * (2.f - a);   // E[(v-am)^2]
        float sc = gamma[c] * rsqrtf(var + 1e-5f);
        sscale[c] = sc;
        sshift[c] = beta[c] - sc * a * m;
    }
    __syncthreads();
    for (int idx = threadIdx.x; idx < 64 * C; idx += 256) {
        int c = idx % C;
        Ag[base + idx] = f2bf(sscale[c] * sm[idx] + sshift[c]);
    }
}

// ---------------- conv1 + GraphNorm1 fused: MFMA 262144x128x64, block = 128 rows = 2 graphs ----------------
__global__ __launch_bounds__(256) void conv1_gn(const short* __restrict__ A, const short* __restrict__ BT,
                                                const float* __restrict__ ri,
                                                const float* __restrict__ alpha, const float* __restrict__ gamma,
                                                const float* __restrict__ beta, short* __restrict__ Outp) {
    __shared__ short As[128][72];
    __shared__ short Bs[128][72];
    __shared__ float sscale[2][128], sshift[2][128];
    const int t = threadIdx.x;
    const int bm = blockIdx.x * 128;
    const int wave = t >> 6, lane = t & 63;
    const int wm = (wave & 1) * 64, wn = (wave >> 1) * 64;
    const int g = wave & 1;
    const int m16 = lane & 15, quad = lane >> 4;
#pragma unroll
    for (int i = 0; i < 4; i++) {
        int idx = t + 256 * i;
        int rr = idx >> 3, kk = (idx & 7) * 8;
        *(s16x8*)&As[rr][kk] = *(const s16x8*)&A[(size_t)(bm + rr) * 64 + kk];
        *(s16x8*)&Bs[rr][kk] = *(const s16x8*)&BT[(size_t)rr * 64 + kk];
    }
    __syncthreads();
    f32x4 acc[4][4] = {};
#pragma unroll
    for (int kc = 0; kc < 2; kc++) {
        s16x8 af[4], bfr[4];
#pragma unroll
        for (int mt = 0; mt < 4; mt++) af[mt] = *(const s16x8*)&As[wm + mt * 16 + m16][kc * 32 + quad * 8];
#pragma unroll
        for (int nt = 0; nt < 4; nt++) bfr[nt] = *(const s16x8*)&Bs[wn + nt * 16 + m16][kc * 32 + quad * 8];
#pragma unroll
        for (int mt = 0; mt < 4; mt++)
#pragma unroll
            for (int nt = 0; nt < 4; nt++)
                acc[mt][nt] = __builtin_amdgcn_mfma_f32_16x16x32_bf16(af[mt], bfr[nt], acc[mt][nt], 0, 0, 0);
    }
#pragma unroll
    for (int mt = 0; mt < 4; mt++)
#pragma unroll
        for (int r4 = 0; r4 < 4; r4++) {
            float rv = ri[bm + wm + mt * 16 + quad * 4 + r4];
#pragma unroll
            for (int nt = 0; nt < 4; nt++)
                acc[mt][nt][r4] = lrelu(acc[mt][nt][r4] * rv);
        }
#pragma unroll
    for (int nt = 0; nt < 4; nt++) {
        float s1 = 0.f, s2 = 0.f;
#pragma unroll
        for (int mt = 0; mt < 4; mt++)
#pragma unroll
            for (int r4 = 0; r4 < 4; r4++) { float v = acc[mt][nt][r4]; s1 += v; s2 += v * v; }
        s1 += __shfl_xor(s1, 16); s1 += __shfl_xor(s1, 32);
        s2 += __shfl_xor(s2, 16); s2 += __shfl_xor(s2, 32);
        if (quad == 0) {
            int ch = wn + nt * 16 + m16;
            float m = s1 * (1.f / 64.f);
            float a = alpha[ch];
            float var = s2 * (1.f / 64.f) - m * m * a * (2.f - a);   // E[(v-am)^2]
            float sc = gamma[ch] * rsqrtf(var + 1e-5f);
            sscale[g][ch] = sc;
            sshift[g][ch] = beta[ch] - sc * a * m;
        }
    }
    __syncthreads();
#pragma unroll
    for (int nt = 0; nt < 4; nt++) {
        int ch = wn + nt * 16 + m16;
        float sc = sscale[g][ch], sh = sshift[g][ch];
#pragma unroll
        for (int mt = 0; mt < 4; mt++)
#pragma unroll
            for (int r4 = 0; r4 < 4; r4++) {
                int row = bm + wm + mt * 16 + quad * 4 + r4;
                Outp[(size_t)row * 128 + ch] = f2bf(sc * acc[mt][nt][r4] + sh);
            }
    }
}

// ---------------- conv2: MFMA GEMM 262144x96x128, A=gn1 bf16, BT=W2T bf16 (96x128), out h2 bf16 ----------------
__global__ __launch_bounds__(256) void conv2_mfma(const short* __restrict__ A, const short* __restrict__ BT,
                                                  short* __restrict__ H) {
    __shared__ short As[128][136];   // 128 k + 8 pad
    __shared__ short Bs[96][136];
    const int t = threadIdx.x;
    const int bm = blockIdx.x * 128;
    const int wave = t >> 6, lane = t & 63;
    const int wm = (wave & 1) * 64, wn = (wave >> 1) * 48;
    const int m16 = lane & 15, quad = lane >> 4;
#pragma unroll
    for (int i = 0; i < 8; i++) {
        int idx = t + 256 * i;
        int rr = idx >> 4, kk = (idx & 15) * 8;
        *(s16x8*)&As[rr][kk] = *(const s16x8*)&A[(size_t)(bm + rr) * 128 + kk];
    }
#pragma unroll
    for (int i = 0; i < 6; i++) {
        int idx = t + 256 * i;
        int nr = idx >> 4, kk = (idx & 15) * 8;
        *(s16x8*)&Bs[nr][kk] = *(const s16x8*)&BT[(size_t)nr * 128 + kk];
    }
    __syncthreads();
    f32x4 acc[4][3] = {};
#pragma unroll
    for (int kc = 0; kc < 4; kc++) {
        s16x8 af[4], bfr[3];
#pragma unroll
        for (int mt = 0; mt < 4; mt++) af[mt] = *(const s16x8*)&As[wm + mt * 16 + m16][kc * 32 + quad * 8];
#pragma unroll
        for (int nt = 0; nt < 3; nt++) bfr[nt] = *(const s16x8*)&Bs[wn + nt * 16 + m16][kc * 32 + quad * 8];
#pragma unroll
        for (int mt = 0; mt < 4; mt++)
#pragma unroll
            for (int nt = 0; nt < 3; nt++)
                acc[mt][nt] = __builtin_amdgcn_mfma_f32_16x16x32_bf16(af[mt], bfr[nt], acc[mt][nt], 0, 0, 0);
    }
#pragma unroll
    for (int mt = 0; mt < 4; mt++)
#pragma unroll
        for (int r4 = 0; r4 < 4; r4++) {
            int row = bm + wm + mt * 16 + quad * 4 + r4;
#pragma unroll
            for (int nt = 0; nt < 3; nt++)
                H[(size_t)row * 96 + wn + nt * 16 + m16] = f2bf(acc[mt][nt][r4]);
        }
}

// ---------------- W fp32 (R x Cc) -> WT bf16 (Cc x R), tiled transpose+convert ----------------
__global__ __launch_bounds__(256) void transp_cvt(const float* __restrict__ W, short* __restrict__ WT,
                                                  int R, int Cc) {
    __shared__ short tile[32][33];
    const int bc = blockIdx.x * 32;   // col of W
    const int br = blockIdx.y * 32;   // row of W
    const int tx = threadIdx.x & 31, ty = threadIdx.x >> 5;   // 32 x 8
#pragma unroll
    for (int i = 0; i < 32; i += 8)
        tile[ty + i][tx] = f2bf(W[(size_t)(br + ty + i) * Cc + bc + tx]);
    __syncthreads();
#pragma unroll
    for (int i = 0; i < 32; i += 8)
        WT[(size_t)(bc + ty + i) * R + br + tx] = tile[tx][ty + i];
}

// ---------------- MLP1: 256x256-tile 8-phase split-K bf16 MFMA GEMM ----------------
// v2 structure (129 us verified) + B-fragment dedup: phases (kc,0) load af+bfr; phases (kc,1)
// load af only and REUSE bfr (b(kc) is identical for both mh halves). Removes 8 of 32
// ds_read_b128 per wave per K-tile. Peak register pressure unchanged (af+bfr+acc live during
// MFMA in both variants; bfr merely stays live where it was previously dead between phases).
#define MBAR() __builtin_amdgcn_s_barrier()
#define LGKM0() asm volatile("s_waitcnt lgkmcnt(0)" ::: "memory")
#define SB0() __builtin_amdgcn_sched_barrier(0)
#define VMC4() asm volatile("s_waitcnt vmcnt(4)" ::: "memory")
#define VMC2() asm volatile("s_waitcnt vmcnt(2)" ::: "memory")
#define VMC0() asm volatile("s_waitcnt vmcnt(0)" ::: "memory")

__global__ __launch_bounds__(512, 2) void mlp1_mfma8(const short* __restrict__ A, const short* __restrict__ BT,
                                                     short* __restrict__ Cp) {
    constexpr int K = INMLP;
    __shared__ short As[2][256 * 64];
    __shared__ short Bs[2][256 * 64];
    const int t = threadIdx.x;
    const int wid = t >> 6, lane = t & 63;
    const int lrow = lane >> 3, lcol = lane & 7;
    const int scol = lcol ^ (lrow & 7);
    const int m16 = lane & 15, quad = lane >> 4, xkey = m16 & 7;
    const int wm = wid & 1, wn = wid >> 1;
    const int sw = (blockIdx.x & 7) * 32 + (blockIdx.x >> 3);
    const int bm = sw & 15, bn = (sw >> 4) & 7, z = sw >> 7;
    const short* gA = A + (size_t)(bm * 256 + lrow) * K + (size_t)z * (K / 2) + scol * 8;
    const short* gB = BT + (size_t)(bn * 256 + lrow) * K + (size_t)z * (K / 2) + scol * 8;

    f32x4 acc[8][4] = {};

#define STG(gp, Xs, s, r0, ko) \
    async16(gp + (size_t)((r0) + wid * 8) * K + (ko), &Xs[s][((r0) + wid * 8) * 64])
#define STAGE_B4(s, ko) { STG(gB, Bs, s, 0, ko); STG(gB, Bs, s, 64, ko); STG(gB, Bs, s, 128, ko); STG(gB, Bs, s, 192, ko); }
#define STAGE_A4(s, ko) { STG(gA, As, s, 0, ko); STG(gA, As, s, 128, ko); STG(gA, As, s, 64, ko); STG(gA, As, s, 192, ko); }
#define LOAD_A(s, kc, mh) \
    { _Pragma("unroll") for (int mt = 0; mt < 4; mt++) \
          af[mt] = *(const s16x8*)&As[s][(wm * 128 + (mh) * 64 + mt * 16 + m16) * 64 + (((kc) * 4 + quad) ^ xkey) * 8]; }
#define LOAD_B(s, kc) \
    { _Pragma("unroll") for (int nt = 0; nt < 4; nt++) \
          bfr[nt] = *(const s16x8*)&Bs[s][(wn * 64 + nt * 16 + m16) * 64 + (((kc) * 4 + quad) ^ xkey) * 8]; }
#define PH_MM(mh) \
    { _Pragma("unroll") for (int mt = 0; mt < 4; mt++) \
          _Pragma("unroll") for (int nt = 0; nt < 4; nt++) \
              acc[(mh) * 4 + mt][nt] = __builtin_amdgcn_mfma_f32_16x16x32_bf16(af[mt], bfr[nt], acc[(mh) * 4 + mt][nt], 0, 0, 0); }

    STAGE_B4(0, 0); STAGE_A4(0, 0);
    VMC2();
    MBAR();

    int kof = 0;
#pragma unroll 1
    for (int i = 0; i < 24; i++, kof += 128) {
        const bool st = (i < 23);
        s16x8 af[4], bfr[4];
        // ph1: slot0 (kc0,mh0) [loads a+b]; stage s1<-B(tile 2i+1)
        LOAD_A(0, 0, 0); LOAD_B(0, 0); STAGE_B4(1, kof + 64);
        MBAR(); LGKM0(); SB0();
        __builtin_amdgcn_s_setprio(1); PH_MM(0); __builtin_amdgcn_s_setprio(0);
        VMC4(); MBAR();
        // ph2: slot0 (kc0,mh1) [reuse b]; stage s1<-A(tile 2i+1)
        LOAD_A(0, 0, 1); STAGE_A4(1, kof + 64);
        MBAR(); LGKM0(); SB0();
        __builtin_amdgcn_s_setprio(1); PH_MM(1); __builtin_amdgcn_s_setprio(0);
        MBAR();
        // ph3: slot0 (kc1,mh0) [loads a+b]
        LOAD_A(0, 1, 0); LOAD_B(0, 1);
        MBAR(); LGKM0(); SB0();
        __builtin_amdgcn_s_setprio(1); PH_MM(0); __builtin_amdgcn_s_setprio(0);
        MBAR();
        // ph4: slot0 (kc1,mh1) [reuse b]; guard s1 B+Ah0u for ph5
        LOAD_A(0, 1, 1);
        MBAR(); LGKM0(); SB0();
        __builtin_amdgcn_s_setprio(1); PH_MM(1); __builtin_amdgcn_s_setprio(0);
        VMC2(); MBAR();
        // ph5: slot1 (kc0,mh0); stage s0<-B(tile 2i+2); guard s1 Ah1u for ph6
        LOAD_A(1, 0, 0); LOAD_B(1, 0);
        if (st) STAGE_B4(0, kof + 128);
        MBAR(); LGKM0(); SB0();
        __builtin_amdgcn_s_setprio(1); PH_MM(0); __builtin_amdgcn_s_setprio(0);
        if (st) { VMC4(); } else { VMC0(); }
        MBAR();
        // ph6: slot1 (kc0,mh1); stage s0<-A(tile 2i+2)
        LOAD_A(1, 0, 1);
        if (st) STAGE_A4(0, kof + 128);
        MBAR(); LGKM0(); SB0();
        __builtin_amdgcn_s_setprio(1); PH_MM(1); __builtin_amdgcn_s_setprio(0);
        MBAR();
        // ph7: slot1 (kc1,mh0)
        LOAD_A(1, 1, 0); LOAD_B(1, 1);
        MBAR(); LGKM0(); SB0();
        __builtin_amdgcn_s_setprio(1); PH_MM(0); __builtin_amdgcn_s_setprio(0);
        MBAR();
        // ph8: slot1 (kc1,mh1); guard s0 B+Ah0u for next ph1
        LOAD_A(1, 1, 1);
        MBAR(); LGKM0(); SB0();
        __builtin_amdgcn_s_setprio(1); PH_MM(1); __builtin_amdgcn_s_setprio(0);
        if (st) { VMC2(); }
        MBAR();
    }

    short* C = Cp + (size_t)z * BB * HID;
    const int r0 = bm * 256 + wm * 128 + quad * 4;
    const int c0 = bn * 256 + wn * 64 + m16;
#pragma unroll
    for (int mt = 0; mt < 8; mt++)
#pragma unroll
        for (int nt = 0; nt < 4; nt++)
#pragma unroll
            for (int r4 = 0; r4 < 4; r4++)
                C[(size_t)(r0 + mt * 16 + r4) * HID + c0 + nt * 16] = f2bf(acc[mt][nt][r4]);
#undef STG
#undef STAGE_A4
#undef STAGE_B4
#undef LOAD_A
#undef LOAD_B
#undef PH_MM
}

// ---------------- combine split-K partials + leaky + InstanceNorm, bf16 in place (D0) ----------------
__global__ __launch_bounds__(256) void rownorm_hid(short* __restrict__ D0, const short* __restrict__ D1) {
    const size_t base = (size_t)blockIdx.x * HID;
    float v[8];
    float s1 = 0.f, s2 = 0.f;
    const int c0 = threadIdx.x * 8;
    {
        s16x8 a = *(const s16x8*)&D0[base + c0];
        s16x8 b = *(const s16x8*)&D1[base + c0];
#pragma unroll
        for (int k = 0; k < 8; k++) {
            float x = lrelu(bf2f(a[k]) + bf2f(b[k]));
            v[k] = x; s1 += x; s2 += x * x;
        }
    }
#pragma unroll
    for (int o = 32; o > 0; o >>= 1) { s1 += __shfl_down(s1, o); s2 += __shfl_down(s2, o); }
    __shared__ float w1[4], w2[4];
    if ((threadIdx.x & 63) == 0) { w1[threadIdx.x >> 6] = s1; w2[threadIdx.x >> 6] = s2; }
    __syncthreads();
    s1 = w1[0] + w1[1] + w1[2] + w1[3];
    s2 = w2[0] + w2[1] + w2[2] + w2[3];
    float m = s1 * (1.f / HID);
    float inv = rsqrtf(s2 * (1.f / HID) - m * m + 1e-5f);
    s16x8 o;
#pragma unroll
    for (int k = 0; k < 8; k++) o[k] = f2bf((v[k] - m) * inv);
    *(s16x8*)&D0[base + c0] = o;
}

// ---------------- generic MFMA GEMM: A bf16 or fp32 (converted on stage), BT bf16, C fp32 ----------------
template <bool ABF16, bool LEAKY>
__global__ __launch_bounds__(256) void mfma_gemm(const float* __restrict__ Af, const short* __restrict__ Ab,
                                                 const short* __restrict__ BT,
                                                 float* __restrict__ C, int M, int Nn, int K) {
    __shared__ short As[64][40];
    __shared__ short Bs[64][40];
    const int t = threadIdx.x;
    const int bm = blockIdx.x * 64, bn = blockIdx.y * 64;
    const int wave = t >> 6, lane = t & 63;
    const int wm = (wave & 1) * 32, wn = (wave >> 1) * 32;
    const int m16 = lane & 15, quad = lane >> 4;
    const int rr = t >> 2, kk = (t & 3) * 8;
    f32x4 acc[2][2] = {};
    for (int k0 = 0; k0 < K; k0 += 32) {
        if (ABF16) {
            *(s16x8*)&As[rr][kk] = *(const s16x8*)&Ab[(size_t)(bm + rr) * K + k0 + kk];
        } else {
            const float* ap = &Af[(size_t)(bm + rr) * K + k0 + kk];
            float4 v0 = *(const float4*)ap;
            float4 v1 = *(const float4*)(ap + 4);
            s16x8 a8;
            a8[0] = f2bf(v0.x); a8[1] = f2bf(v0.y); a8[2] = f2bf(v0.z); a8[3] = f2bf(v0.w);
            a8[4] = f2bf(v1.x); a8[5] = f2bf(v1.y); a8[6] = f2bf(v1.z); a8[7] = f2bf(v1.w);
            *(s16x8*)&As[rr][kk] = a8;
        }
        *(s16x8*)&Bs[rr][kk] = *(const s16x8*)&BT[(size_t)(bn + rr) * K + k0 + kk];
        __syncthreads();
        s16x8 af[2], bfr[2];
#pragma unroll
        for (int mt = 0; mt < 2; mt++) af[mt] = *(const s16x8*)&As[wm + mt * 16 + m16][quad * 8];
#pragma unroll
        for (int nt = 0; nt < 2; nt++) bfr[nt] = *(const s16x8*)&Bs[wn + nt * 16 + m16][quad * 8];
#pragma unroll
        for (int mt = 0; mt < 2; mt++)
#pragma unroll
            for (int nt = 0; nt < 2; nt++)
                acc[mt][nt] = __builtin_amdgcn_mfma_f32_16x16x32_bf16(af[mt], bfr[nt], acc[mt][nt], 0, 0, 0);
        __syncthreads();
    }
#pragma unroll
    for (int mt = 0; mt < 2; mt++)
#pragma unroll
        for (int nt = 0; nt < 2; nt++)
#pragma unroll
            for (int r4 = 0; r4 < 4; r4++) {
                int row = bm + wm + mt * 16 + quad * 4 + r4;
                int col = bn + wn + nt * 16 + m16;
                float v = acc[mt][nt][r4];
                if (LEAKY) v = lrelu(v);
                C[(size_t)row * Nn + col] = v;
            }
}

// ---------------- per-row InstanceNorm (in place, fp32) ----------------
template <int NC>
__global__ __launch_bounds__(256) void rownorm(float* __restrict__ Y) {
    float* p = Y + (size_t)blockIdx.x * NC;
    float s1 = 0.f, s2 = 0.f;
    for (int c = threadIdx.x; c < NC; c += 256) { float v = p[c]; s1 += v; s2 += v * v; }
#pragma unroll
    for (int o = 32; o > 0; o >>= 1) { s1 += __shfl_down(s1, o); s2 += __shfl_down(s2, o); }
    __shared__ float w1[4], w2[4];
    if ((threadIdx.x & 63) == 0) { w1[threadIdx.x >> 6] = s1; w2[threadIdx.x >> 6] = s2; }
    __syncthreads();
    s1 = w1[0] + w1[1] + w1[2] + w1[3];
    s2 = w2[0] + w2[1] + w2[2] + w2[3];
    float m = s1 * (1.f / NC);
    float inv = rsqrtf(s2 * (1.f / NC) - m * m + 1e-5f);
    for (int c = threadIdx.x; c < NC; c += 256) p[c] = (p[c] - m) * inv;
}

extern "C" void kernel_launch(void* const* d_in, const int* in_sizes, int n_in,
                              void* d_out, int out_size, void* d_ws, size_t ws_size,
                              hipStream_t stream) {
    const float* x    = (const float*)d_in[0];
    const float* ew   = (const float*)d_in[1];
    const int*   src  = (const int*)d_in[2];
    const int*   dst  = (const int*)d_in[3];
    const float* W1   = (const float*)d_in[4];
    const float* W2   = (const float*)d_in[5];
    const float* a1   = (const float*)d_in[6];
    const float* g1   = (const float*)d_in[7];
    const float* b1   = (const float*)d_in[8];
    const float* a2   = (const float*)d_in[9];
    const float* g2   = (const float*)d_in[10];
    const float* b2   = (const float*)d_in[11];
    const float* Win  = (const float*)d_in[12];
    const float* Whid = (const float*)d_in[13];
    const float* Wcls = (const float*)d_in[14];
    float* out = (float*)d_out;

    // ---- workspace layout ----
    float* ro   = (float*)d_ws;                    // NN
    float* ri   = ro + NN;                         // NN
    int*   din  = (int*)(ri + NN);                 // NN (deg_in for scan)
    int*   offs = din + NN;                        // NN+4
    int*   blks = offs + NN + 4;                   // 256
    short* w1t  = (short*)(blks + 256);            // 128*64 bf16
    short* w2t  = w1t + 128 * 64;                  // 96*128 bf16
    int2*  edg  = (int2*)(((size_t)(w2t + 96 * 128) + 15) & ~(size_t)15);   // EE int2 (src, ew*ro), 16.8 MB
    short* Abf  = (short*)(edg + EE);              // 64 MiB region
    short* Bbf  = Abf + (size_t)NN * 128;          // 64 MiB region
    short* xbf  = Abf;                             // NN*64
    short* aggx = Abf + (size_t)NN * 64;           // NN*64
    // graph-build temps: u8-packed part arrays in Abf; repbase+rank in Bbf
    unsigned*       part_din   = (unsigned*)Abf;                       // NSL * NN/4 words (16 MiB)
    unsigned*       part_dout  = part_din + (size_t)NSL * (NN / 4);    // 16 MiB
    unsigned*       repbase_w  = (unsigned*)Bbf;                       // 32 MiB
    unsigned short* rankpack16 = (unsigned short*)(repbase_w + (size_t)NSL * (NN / 2));  // EE u16
    // overlays into Abf region after gather96 (h2 dead):
    short* WinT = Abf;                                      // 2048*6144 bf16 = 25165824 B
    short* D0   = (short*)((char*)Abf + 25165824);          // 4096*2048 bf16 = 16777216 B
    short* D1   = D0 + (size_t)BB * HID;                    // 4096*2048 bf16 = 16777216 B  (total 58.7 MB <= 64 MiB)
    // Y2 in edg region (edg dead after gather96):
    float* Y2   = (float*)edg;                              // 4096*512 fp32 = 8388608 B <= 16.8 MB
    // overlays into Bbf region after mlp1_mfma8 consumes gn2:
    short* WhidT = Bbf;                            // 512*2048 bf16
    short* WclsT = WhidT + (size_t)HID4 * HID;     // 256*512 bf16

    // 1) degrees + per-edge ranks via u8 LDS histograms (512 blocks, int4 streaming)
    hist_count<<<2 * 4 * NSL, 256, 0, stream>>>(dst, src, part_din, part_dout, rankpack16);
    deg_reduce<<<NN / 1024, 256, 0, stream>>>(part_din, part_dout, repbase_w, ro, ri, din);

    // 2) CSR by dst: scan + atomic-free fill
    scanA<<<NN / 1024, 256, 0, stream>>>(din, blks);
    scanB<<<1, 256, 0, stream>>>(blks, offs + NN);
    scanC<<<NN / 1024, 256, 0, stream>>>(din, blks, offs);
    fill_csr<<<EE / 256, 256, 0, stream>>>(src, dst, ew, ro, offs,
                                           (const unsigned short*)repbase_w, rankpack16, edg);

    // 3) conv layer 1: gather x (64 dims), then GEMM + fused GraphNorm1
    cvt_x<<<NN * 64 / 1024, 256, 0, stream>>>(x, xbf);
    transp_cvt<<<dim3(128 / 32, 64 / 32), 256, 0, stream>>>(W1, w1t, 64, 128);
    gather64<<<NN / 4, 256, 0, stream>>>(xbf, offs, edg, aggx);
    conv1_gn<<<NN / 128, 256, 0, stream>>>(aggx, w1t, ri, a1, g1, b1, Bbf);   // Bbf = gn1

    // 4) conv layer 2: GEMM, then wave-per-node gather, then GraphNorm2
    transp_cvt<<<dim3(96 / 32, 128 / 32), 256, 0, stream>>>(W2, w2t, 128, 96);
    conv2_mfma<<<NN / 128, 256, 0, stream>>>(Bbf, w2t, Abf);                  // h2 (xbf/aggx dead)
    gather96<<<NN / 4, 256, 0, stream>>>(Abf, offs, edg, Bbf);                // Bbf = agg2 (gn1 dead)
    graphnorm_k<96><<<BB, 256, 0, stream>>>(Bbf, ri, a2, g2, b2);             // Bbf = gn2 (MLP input)

    // 5) MLP
    transp_cvt<<<dim3(HID / 32, INMLP / 32), 256, 0, stream>>>(Win, WinT, INMLP, HID);
    mlp1_mfma8<<<256, 512, 0, stream>>>(Bbf, WinT, D0);                       // 8-phase split-K partials
    transp_cvt<<<dim3(HID4 / 32, HID / 32), 256, 0, stream>>>(Whid, WhidT, HID, HID4);
    transp_cvt<<<dim3(OUTF / 32, HID4 / 32), 256, 0, stream>>>(Wcls, WclsT, HID4, OUTF);
    rownorm_hid<<<BB, 256, 0, stream>>>(D0, D1);                                  // D0 = norm(lrelu(D0+D1)) bf16
    mfma_gemm<true, true><<<dim3(BB / 64, HID4 / 64), 256, 0, stream>>>(nullptr, D0, WhidT, Y2, BB, HID4, HID);
    rownorm<HID4><<<BB, 256, 0, stream>>>(Y2);
    mfma_gemm<false, false><<<dim3(BB / 64, OUTF / 64), 256, 0, stream>>>(Y2, nullptr, WclsT, out, BB, OUTF, HID4);
}

// Round 8
// 757.424 us; speedup vs baseline: 1.1986x; 1.0153x over previous
//
#include <hip/hip_runtime.h>
#include <hip/hip_bf16.h>

// Problem constants (fixed-shape problem)
#define NN 262144      // nodes = 4096 graphs * 64
#define EE 2097152     // edges
#define BB 4096        // graphs
constexpr int INMLP = 6144;
constexpr int HID = 2048;
constexpr int HID4 = 512;
constexpr int OUTF = 256;
constexpr int NSL = 64;            // edge slices
constexpr int ESL = EE / NSL;      // 32768 edges per slice
constexpr int RN4 = 65536;         // nodes per range (4 ranges, u8 counters in 64 KB LDS)

typedef short s16x8 __attribute__((ext_vector_type(8)));   // 8 bf16 in 4 VGPRs
typedef short s16x4 __attribute__((ext_vector_type(4)));
typedef float f32x4 __attribute__((ext_vector_type(4)));

__device__ __forceinline__ float lrelu(float v) { return v >= 0.f ? v : 0.01f * v; }
__device__ __forceinline__ float bf2f(short s) {
    unsigned int u = ((unsigned int)(unsigned short)s) << 16;
    return __builtin_bit_cast(float, u);
}
__device__ __forceinline__ short f2bf(float f) {   // RNE
    unsigned int u = __builtin_bit_cast(unsigned int, f);
    u = (u + 0x7fff + ((u >> 16) & 1)) >> 16;
    return (short)u;
}
// async global->LDS, 16B per lane. LDS dest = wave-uniform base + lane*16.
__device__ __forceinline__ void async16(const void* g, void* l) {
    __builtin_amdgcn_global_load_lds((__attribute__((address_space(1))) void*)g,
                                     (__attribute__((address_space(3))) void*)l, 16, 0, 0);
}

// ---------------- degree counting via LDS u8 histograms (4 ranges, 2 types = 8 passes) ----------------
__global__ __launch_bounds__(256) void hist_count(const int* __restrict__ dst, const int* __restrict__ src,
                                                  unsigned* __restrict__ part_din, unsigned* __restrict__ part_dout,
                                                  unsigned short* __restrict__ rankpack16) {
    __shared__ unsigned hist[RN4 / 4];   // 65536 B (u8 lanes in u32)
    const int S = blockIdx.x & 63;
    const int R = (blockIdx.x >> 6) & 3;
    const int T = blockIdx.x >> 8;          // 0 = din(dst)+rank, 1 = dout(src)
    for (int i = threadIdx.x; i < RN4 / 4; i += 256) hist[i] = 0;
    __syncthreads();
    const int* idxarr = T ? src : dst;
    const int4* v4 = (const int4*)(idxarr + S * ESL);
#pragma unroll 4
    for (int i = 0; i < ESL / 4 / 256; i++) {            // 32 iterations
        const int q0 = i * 256 + threadIdx.x;
        int4 q = v4[q0];
        const int ebase = S * ESL + q0 * 4;
#pragma unroll
        for (int k = 0; k < 4; k++) {
            int idx = k == 0 ? q.x : k == 1 ? q.y : k == 2 ? q.z : q.w;
            if ((idx >> 16) == R) {
                int local = idx & (RN4 - 1);
                unsigned old = atomicAdd(&hist[local >> 2], 1u << ((local & 3) * 8));
                if (T == 0) {
                    unsigned rank = (old >> ((local & 3) * 8)) & 0xffu;
                    rankpack16[ebase + k] = (unsigned short)((S << 10) | rank);   // rank <= 255 < 1024
                }
            }
        }
    }
    __syncthreads();
    unsigned* dp = (T ? part_dout : part_din) + (size_t)S * (NN / 4) + R * (RN4 / 4);
    for (int i = threadIdx.x; i < RN4 / 4; i += 256) dp[i] = hist[i];
}

// ---------------- reduce slices: degrees, rsqrt factors, per-(slice,node) base offsets ----------------
__global__ __launch_bounds__(256) void deg_reduce(const unsigned* __restrict__ part_din,
                                                  const unsigned* __restrict__ part_dout,
                                                  unsigned* __restrict__ repbase_w,   // [NSL][NN/2] packed u16
                                                  float* __restrict__ ro, float* __restrict__ ri,
                                                  int* __restrict__ din) {
    int i = blockIdx.x * 256 + threadIdx.x;    // u8-word index over NN/4
    unsigned r0 = 0, r1 = 0, r2 = 0, r3 = 0, d0 = 0, d1 = 0, d2 = 0, d3 = 0;
#pragma unroll 8
    for (int S = 0; S < NSL; S++) {
        repbase_w[(size_t)S * (NN / 2) + 2 * i]     = (r0 & 0xffffu) | ((r1 & 0xffffu) << 16);
        repbase_w[(size_t)S * (NN / 2) + 2 * i + 1] = (r2 & 0xffffu) | ((r3 & 0xffffu) << 16);
        unsigned w = part_din[(size_t)S * (NN / 4) + i];
        r0 += w & 0xffu; r1 += (w >> 8) & 0xffu; r2 += (w >> 16) & 0xffu; r3 += w >> 24;
        unsigned w2 = part_dout[(size_t)S * (NN / 4) + i];
        d0 += w2 & 0xffu; d1 += (w2 >> 8) & 0xffu; d2 += (w2 >> 16) & 0xffu; d3 += w2 >> 24;
    }
    int n = 4 * i;
    *(int4*)&din[n] = make_int4((int)r0, (int)r1, (int)r2, (int)r3);
    float4 vo, vi;
    vo.x = rsqrtf((float)(d0 < 1u ? 1u : d0)); vo.y = rsqrtf((float)(d1 < 1u ? 1u : d1));
    vo.z = rsqrtf((float)(d2 < 1u ? 1u : d2)); vo.w = rsqrtf((float)(d3 < 1u ? 1u : d3));
    vi.x = rsqrtf((float)(r0 < 1u ? 1u : r0)); vi.y = rsqrtf((float)(r1 < 1u ? 1u : r1));
    vi.z = rsqrtf((float)(r2 < 1u ? 1u : r2)); vi.w = rsqrtf((float)(r3 < 1u ? 1u : r3));
    *(float4*)&ro[n] = vo;
    *(float4*)&ri[n] = vi;
}

// ---------------- scan (exclusive prefix over din counts -> CSR offsets) ----------------
__global__ __launch_bounds__(256) void scanA(const int* __restrict__ cnt, int* __restrict__ blks) {
    __shared__ int s[256];
    int t = threadIdx.x;
    int i0 = blockIdx.x * 1024 + t * 4;
    int ts = cnt[i0] + cnt[i0 + 1] + cnt[i0 + 2] + cnt[i0 + 3];
    s[t] = ts; __syncthreads();
    for (int d = 128; d > 0; d >>= 1) { if (t < d) s[t] += s[t + d]; __syncthreads(); }
    if (t == 0) blks[blockIdx.x] = s[0];
}

__global__ __launch_bounds__(256) void scanB(int* __restrict__ blks, int* __restrict__ offN) {
    __shared__ int s[256];
    int t = threadIdx.x;
    int v = blks[t]; s[t] = v; __syncthreads();
    for (int d = 1; d < 256; d <<= 1) {
        int x = (t >= d) ? s[t - d] : 0; __syncthreads();
        s[t] += x; __syncthreads();
    }
    blks[t] = s[t] - v;            // exclusive
    if (t == 255) *offN = s[255];  // total = EE
}

__global__ __launch_bounds__(256) void scanC(const int* __restrict__ cnt, const int* __restrict__ blkoff,
                                             int* __restrict__ off) {
    __shared__ int s[256];
    int t = threadIdx.x;
    int i0 = blockIdx.x * 1024 + t * 4;
    int v0 = cnt[i0], v1 = cnt[i0 + 1], v2 = cnt[i0 + 2], v3 = cnt[i0 + 3];
    int ts = v0 + v1 + v2 + v3;
    s[t] = ts; __syncthreads();
    for (int d = 1; d < 256; d <<= 1) {
        int x = (t >= d) ? s[t - d] : 0; __syncthreads();
        s[t] += x; __syncthreads();
    }
    int base = blkoff[blockIdx.x] + (s[t] - ts);
    off[i0] = base; off[i0 + 1] = base + v0; off[i0 + 2] = base + v0 + v1; off[i0 + 3] = base + v0 + v1 + v2;
}

// ---------------- fill CSR: atomic-free scatter via (slice, rank) + repbase ----------------
__global__ __launch_bounds__(256) void fill_csr(const int* __restrict__ src, const int* __restrict__ dst,
                                                const float* __restrict__ ew, const float* __restrict__ ro,
                                                const int* __restrict__ off,
                                                const unsigned short* __restrict__ repbase16,  // [NSL][NN]
                                                const unsigned short* __restrict__ rankpack16,
                                                int2* __restrict__ edg) {
    int e = blockIdx.x * 256 + threadIdx.x;
    int d = dst[e];
    int s = src[e];
    unsigned pk = rankpack16[e];
    int S = pk >> 10, rank = pk & 1023;
    int p = off[d] + (int)repbase16[(size_t)S * NN + d] + rank;
    edg[p] = make_int2(s, __builtin_bit_cast(int, ew[e] * ro[s]));
}

// ---------------- x fp32 -> bf16 ----------------
__global__ __launch_bounds__(256) void cvt_x(const float* __restrict__ X, short* __restrict__ Xb) {
    int i = (blockIdx.x * 256 + threadIdx.x) * 4;
    float4 v = *(const float4*)(X + i);
    s16x4 o = { f2bf(v.x), f2bf(v.y), f2bf(v.z), f2bf(v.w) };
    *(s16x4*)(Xb + i) = o;
}

// ---------------- gather 64 dims, wave-per-node, edge-parallel 8 edges x 8 chunks of 8 dims ----------------
__global__ __launch_bounds__(256) void gather64(const short* __restrict__ Xb, const int* __restrict__ offs,
                                                const int2* __restrict__ edg, short* __restrict__ Out) {
    const int lane = threadIdx.x & 63;
    const int e = lane >> 3, c = lane & 7;
    int node = blockIdx.x * 4 + (threadIdx.x >> 6);
    node = __builtin_amdgcn_readfirstlane(node);
    const int s0 = offs[node], s1 = offs[node + 1];
    float acc[8] = {};
    for (int j0 = s0; j0 < s1; j0 += 8) {
        int j = j0 + e;
        bool ok = j < s1;
        int2 pe = edg[ok ? j : s0];
        int s = pe.x;
        float w = ok ? __builtin_bit_cast(float, pe.y) : 0.f;
        s16x8 v = *(const s16x8*)&Xb[(size_t)s * 64 + c * 8];
#pragma unroll
        for (int k = 0; k < 8; k++) acc[k] = fmaf(w, bf2f(v[k]), acc[k]);
    }
#pragma unroll
    for (int off = 8; off <= 32; off <<= 1)
#pragma unroll
        for (int k = 0; k < 8; k++) acc[k] += __shfl_xor(acc[k], off);
    if (e == 0) {
        s16x8 o;
#pragma unroll
        for (int k = 0; k < 8; k++) o[k] = f2bf(acc[k]);
        *(s16x8*)&Out[(size_t)node * 64 + c * 8] = o;
    }
}

// ---------------- gather 96 dims, wave-per-node, edge-parallel 4 edges x 16 chunks of 6 dims ----------------
__global__ __launch_bounds__(256) void gather96(const short* __restrict__ H, const int* __restrict__ offs,
                                                const int2* __restrict__ edg, short* __restrict__ Out) {
    const int lane = threadIdx.x & 63;
    const int e = lane >> 4, c = lane & 15;
    int node = blockIdx.x * 4 + (threadIdx.x >> 6);
    node = __builtin_amdgcn_readfirstlane(node);
    const int s0 = offs[node], s1 = offs[node + 1];
    float acc[6] = {};
    for (int j0 = s0; j0 < s1; j0 += 4) {
        int j = j0 + e;
        bool ok = j < s1;
        int2 pe = edg[ok ? j : s0];
        int s = pe.x;
        float w = ok ? __builtin_bit_cast(float, pe.y) : 0.f;
        const unsigned int* hp = (const unsigned int*)(H + (size_t)s * 96 + c * 6);
        unsigned int u0 = hp[0], u1 = hp[1], u2 = hp[2];
        acc[0] = fmaf(w, bf2f((short)(u0 & 0xffff)), acc[0]);
        acc[1] = fmaf(w, bf2f((short)(u0 >> 16)), acc[1]);
        acc[2] = fmaf(w, bf2f((short)(u1 & 0xffff)), acc[2]);
        acc[3] = fmaf(w, bf2f((short)(u1 >> 16)), acc[3]);
        acc[4] = fmaf(w, bf2f((short)(u2 & 0xffff)), acc[4]);
        acc[5] = fmaf(w, bf2f((short)(u2 >> 16)), acc[5]);
    }
#pragma unroll
    for (int off = 16; off <= 32; off <<= 1)
#pragma unroll
        for (int k = 0; k < 6; k++) acc[k] += __shfl_xor(acc[k], off);
    if (e == 0) {
        unsigned int* op = (unsigned int*)(Out + (size_t)node * 96 + c * 6);
        op[0] = (unsigned short)f2bf(acc[0]) | ((unsigned)(unsigned short)f2bf(acc[1]) << 16);
        op[1] = (unsigned short)f2bf(acc[2]) | ((unsigned)(unsigned short)f2bf(acc[3]) << 16);
        op[2] = (unsigned short)f2bf(acc[4]) | ((unsigned)(unsigned short)f2bf(acc[5]) << 16);
    }
}

// ---------------- fused rsqrt(deg_in)*leaky_relu + GraphNorm (per 64-node graph), bf16 in place ----------------
template <int C>
__global__ __launch_bounds__(256) void graphnorm_k(short* __restrict__ Ag, const float* __restrict__ ri,
                                                   const float* __restrict__ alpha, const float* __restrict__ gamma,
                                                   const float* __restrict__ beta) {
    __shared__ float sm[64 * C];
    __shared__ float sscale[C], sshift[C];
    const int g = blockIdx.x;
    const size_t base = (size_t)g * 64 * C;
    for (int idx = threadIdx.x; idx < 64 * C; idx += 256) {
        int i = idx / C;
        float v = bf2f(Ag[base + idx]) * ri[g * 64 + i];
        sm[idx] = lrelu(v);
    }
    __syncthreads();
    if (threadIdx.x < C) {
        int c = threadIdx.x;
        float s1 = 0.f, s2 = 0.f;
#pragma unroll 4
        for (int i = 0; i < 64; i++) { float v = sm[i * C + c]; s1 += v; s2 += v * v; }
        float m = s1 * (1.f / 64.f);
        float a = alpha[c];
        float var = s2 * (1.f / 64.f) - m * m * a * (2.f - a);   // E[(v-am)^2]
        float sc = gamma[c] * rsqrtf(var + 1e-5f);
        sscale[c] = sc;
        sshift[c] = beta[c] - sc * a * m;
    }
    __syncthreads();
    for (int idx = threadIdx.x; idx < 64 * C; idx += 256) {
        int c = idx % C;
        Ag[base + idx] = f2bf(sscale[c] * sm[idx] + sshift[c]);
    }
}

// ---------------- conv1 + GraphNorm1 fused: MFMA 262144x128x64, block = 128 rows = 2 graphs ----------------
__global__ __launch_bounds__(256) void conv1_gn(const short* __restrict__ A, const short* __restrict__ BT,
                                                const float* __restrict__ ri,
                                                const float* __restrict__ alpha, const float* __restrict__ gamma,
                                                const float* __restrict__ beta, short* __restrict__ Outp) {
    __shared__ short As[128][72];
    __shared__ short Bs[128][72];
    __shared__ float sscale[2][128], sshift[2][128];
    const int t = threadIdx.x;
    const int bm = blockIdx.x * 128;
    const int wave = t >> 6, lane = t & 63;
    const int wm = (wave & 1) * 64, wn = (wave >> 1) * 64;
    const int g = wave & 1;
    const int m16 = lane & 15, quad = lane >> 4;
#pragma unroll
    for (int i = 0; i < 4; i++) {
        int idx = t + 256 * i;
        int rr = idx >> 3, kk = (idx & 7) * 8;
        *(s16x8*)&As[rr][kk] = *(const s16x8*)&A[(size_t)(bm + rr) * 64 + kk];
        *(s16x8*)&Bs[rr][kk] = *(const s16x8*)&BT[(size_t)rr * 64 + kk];
    }
    __syncthreads();
    f32x4 acc[4][4] = {};
#pragma unroll
    for (int kc = 0; kc < 2; kc++) {
        s16x8 af[4], bfr[4];
#pragma unroll
        for (int mt = 0; mt < 4; mt++) af[mt] = *(const s16x8*)&As[wm + mt * 16 + m16][kc * 32 + quad * 8];
#pragma unroll
        for (int nt = 0; nt < 4; nt++) bfr[nt] = *(const s16x8*)&Bs[wn + nt * 16 + m16][kc * 32 + quad * 8];
#pragma unroll
        for (int mt = 0; mt < 4; mt++)
#pragma unroll
            for (int nt = 0; nt < 4; nt++)
                acc[mt][nt] = __builtin_amdgcn_mfma_f32_16x16x32_bf16(af[mt], bfr[nt], acc[mt][nt], 0, 0, 0);
    }
#pragma unroll
    for (int mt = 0; mt < 4; mt++)
#pragma unroll
        for (int r4 = 0; r4 < 4; r4++) {
            float rv = ri[bm + wm + mt * 16 + quad * 4 + r4];
#pragma unroll
            for (int nt = 0; nt < 4; nt++)
                acc[mt][nt][r4] = lrelu(acc[mt][nt][r4] * rv);
        }
#pragma unroll
    for (int nt = 0; nt < 4; nt++) {
        float s1 = 0.f, s2 = 0.f;
#pragma unroll
        for (int mt = 0; mt < 4; mt++)
#pragma unroll
            for (int r4 = 0; r4 < 4; r4++) { float v = acc[mt][nt][r4]; s1 += v; s2 += v * v; }
        s1 += __shfl_xor(s1, 16); s1 += __shfl_xor(s1, 32);
        s2 += __shfl_xor(s2, 16); s2 += __shfl_xor(s2, 32);
        if (quad == 0) {
            int ch = wn + nt * 16 + m16;
            float m = s1 * (1.f / 64.f);
            float a = alpha[ch];
            float var = s2 * (1.f / 64.f) - m * m * a * (2.f - a);   // E[(v-am)^2]
            float sc = gamma[ch] * rsqrtf(var + 1e-5f);
            sscale[g][ch] = sc;
            sshift[g][ch] = beta[ch] - sc * a * m;
        }
    }
    __syncthreads();
#pragma unroll
    for (int nt = 0; nt < 4; nt++) {
        int ch = wn + nt * 16 + m16;
        float sc = sscale[g][ch], sh = sshift[g][ch];
#pragma unroll
        for (int mt = 0; mt < 4; mt++)
#pragma unroll
            for (int r4 = 0; r4 < 4; r4++) {
                int row = bm + wm + mt * 16 + quad * 4 + r4;
                Outp[(size_t)row * 128 + ch] = f2bf(sc * acc[mt][nt][r4] + sh);
            }
    }
}

// ---------------- conv2: MFMA GEMM 262144x96x128, A=gn1 bf16, BT=W2T bf16 (96x128), out h2 bf16 ----------------
__global__ __launch_bounds__(256) void conv2_mfma(const short* __restrict__ A, const short* __restrict__ BT,
                                                  short* __restrict__ H) {
    __shared__ short As[128][136];   // 128 k + 8 pad
    __shared__ short Bs[96][136];
    const int t = threadIdx.x;
    const int bm = blockIdx.x * 128;
    const int wave = t >> 6, lane = t & 63;
    const int wm = (wave & 1) * 64, wn = (wave >> 1) * 48;
    const int m16 = lane & 15, quad = lane >> 4;
#pragma unroll
    for (int i = 0; i < 8; i++) {
        int idx = t + 256 * i;
        int rr = idx >> 4, kk = (idx & 15) * 8;
        *(s16x8*)&As[rr][kk] = *(const s16x8*)&A[(size_t)(bm + rr) * 128 + kk];
    }
#pragma unroll
    for (int i = 0; i < 6; i++) {
        int idx = t + 256 * i;
        int nr = idx >> 4, kk = (idx & 15) * 8;
        *(s16x8*)&Bs[nr][kk] = *(const s16x8*)&BT[(size_t)nr * 128 + kk];
    }
    __syncthreads();
    f32x4 acc[4][3] = {};
#pragma unroll
    for (int kc = 0; kc < 4; kc++) {
        s16x8 af[4], bfr[3];
#pragma unroll
        for (int mt = 0; mt < 4; mt++) af[mt] = *(const s16x8*)&As[wm + mt * 16 + m16][kc * 32 + quad * 8];
#pragma unroll
        for (int nt = 0; nt < 3; nt++) bfr[nt] = *(const s16x8*)&Bs[wn + nt * 16 + m16][kc * 32 + quad * 8];
#pragma unroll
        for (int mt = 0; mt < 4; mt++)
#pragma unroll
            for (int nt = 0; nt < 3; nt++)
                acc[mt][nt] = __builtin_amdgcn_mfma_f32_16x16x32_bf16(af[mt], bfr[nt], acc[mt][nt], 0, 0, 0);
    }
#pragma unroll
    for (int mt = 0; mt < 4; mt++)
#pragma unroll
        for (int r4 = 0; r4 < 4; r4++) {
            int row = bm + wm + mt * 16 + quad * 4 + r4;
#pragma unroll
            for (int nt = 0; nt < 3; nt++)
                H[(size_t)row * 96 + wn + nt * 16 + m16] = f2bf(acc[mt][nt][r4]);
        }
}

// ---------------- W fp32 (R x Cc) -> WT bf16 (Cc x R), tiled transpose+convert ----------------
__global__ __launch_bounds__(256) void transp_cvt(const float* __restrict__ W, short* __restrict__ WT,
                                                  int R, int Cc) {
    __shared__ short tile[32][33];
    const int bc = blockIdx.x * 32;   // col of W
    const int br = blockIdx.y * 32;   // row of W
    const int tx = threadIdx.x & 31, ty = threadIdx.x >> 5;   // 32 x 8
#pragma unroll
    for (int i = 0; i < 32; i += 8)
        tile[ty + i][tx] = f2bf(W[(size_t)(br + ty + i) * Cc + bc + tx]);
    __syncthreads();
#pragma unroll
    for (int i = 0; i < 32; i += 8)
        WT[(size_t)(bc + ty + i) * R + br + tx] = tile[tx][ty + i];
}

// ---------------- MLP1: 256x256-tile 8-phase split-K bf16 MFMA GEMM ----------------
// v4 = round-2 v2 (129 us verified) with the REDUNDANT mid-phase barrier removed. Hazard audit:
// every stage-vs-reader ordering routes through the END-of-phase barrier (last reader's own
// lgkmcnt(0) precedes it; the stage issue follows it), and staged-data reads are guarded by the
// counted vmcnt placed BEFORE that barrier. The mid-phase barrier (between ds-read issue and MFMA)
// carried no hazard - only lockstep. Removing it saves 8 barriers/iter and lets fast waves drift
// into the next phase's ds_reads while slow waves finish MFMA (reads || MFMA overlap via skew).
// lgkmcnt(0)+sched_barrier(0) fence retained (rule #18: MFMA must not hoist past the lgkm wait).
#define MBAR() __builtin_amdgcn_s_barrier()
#define LGKM0() asm volatile("s_waitcnt lgkmcnt(0)" ::: "memory")
#define SB0() __builtin_amdgcn_sched_barrier(0)
#define VMC4() asm volatile("s_waitcnt vmcnt(4)" ::: "memory")
#define VMC2() asm volatile("s_waitcnt vmcnt(2)" ::: "memory")
#define VMC0() asm volatile("s_waitcnt vmcnt(0)" ::: "memory")

__global__ __launch_bounds__(512, 2) void mlp1_mfma8(const short* __restrict__ A, const short* __restrict__ BT,
                                                     short* __restrict__ Cp) {
    constexpr int K = INMLP;
    __shared__ short As[2][256 * 64];
    __shared__ short Bs[2][256 * 64];
    const int t = threadIdx.x;
    const int wid = t >> 6, lane = t & 63;
    const int lrow = lane >> 3, lcol = lane & 7;
    const int scol = lcol ^ (lrow & 7);
    const int m16 = lane & 15, quad = lane >> 4, xkey = m16 & 7;
    const int wm = wid & 1, wn = wid >> 1;
    const int sw = (blockIdx.x & 7) * 32 + (blockIdx.x >> 3);
    const int bm = sw & 15, bn = (sw >> 4) & 7, z = sw >> 7;
    const short* gA = A + (size_t)(bm * 256 + lrow) * K + (size_t)z * (K / 2) + scol * 8;
    const short* gB = BT + (size_t)(bn * 256 + lrow) * K + (size_t)z * (K / 2) + scol * 8;

    f32x4 acc[8][4] = {};

#define STG(gp, Xs, s, r0, ko) \
    async16(gp + (size_t)((r0) + wid * 8) * K + (ko), &Xs[s][((r0) + wid * 8) * 64])
#define STAGE_B4(s, ko) { STG(gB, Bs, s, 0, ko); STG(gB, Bs, s, 64, ko); STG(gB, Bs, s, 128, ko); STG(gB, Bs, s, 192, ko); }
#define STAGE_A4(s, ko) { STG(gA, As, s, 0, ko); STG(gA, As, s, 128, ko); STG(gA, As, s, 64, ko); STG(gA, As, s, 192, ko); }
#define PH_LOAD(s, kc, mh) \
    { _Pragma("unroll") for (int mt = 0; mt < 4; mt++) \
          af[mt] = *(const s16x8*)&As[s][(wm * 128 + (mh) * 64 + mt * 16 + m16) * 64 + (((kc) * 4 + quad) ^ xkey) * 8]; \
      _Pragma("unroll") for (int nt = 0; nt < 4; nt++) \
          bfr[nt] = *(const s16x8*)&Bs[s][(wn * 64 + nt * 16 + m16) * 64 + (((kc) * 4 + quad) ^ xkey) * 8]; }
#define PH_MM(mh) \
    { _Pragma("unroll") for (int mt = 0; mt < 4; mt++) \
          _Pragma("unroll") for (int nt = 0; nt < 4; nt++) \
              acc[(mh) * 4 + mt][nt] = __builtin_amdgcn_mfma_f32_16x16x32_bf16(af[mt], bfr[nt], acc[(mh) * 4 + mt][nt], 0, 0, 0); }

    STAGE_B4(0, 0); STAGE_A4(0, 0);
    VMC2();
    MBAR();

    int kof = 0;
#pragma unroll 1
    for (int i = 0; i < 24; i++, kof += 128) {
        const bool st = (i < 23);
        s16x8 af[4], bfr[4];
        // ph1: slot0 (kc0,mh0); stage s1<-B(tile 2i+1)
        PH_LOAD(0, 0, 0); STAGE_B4(1, kof + 64);
        LGKM0(); SB0();
        __builtin_amdgcn_s_setprio(1); PH_MM(0); __builtin_amdgcn_s_setprio(0);
        VMC4(); MBAR();
        // ph2: slot0 (kc0,mh1); stage s1<-A(tile 2i+1)
        PH_LOAD(0, 0, 1); STAGE_A4(1, kof + 64);
        LGKM0(); SB0();
        __builtin_amdgcn_s_setprio(1); PH_MM(1); __builtin_amdgcn_s_setprio(0);
        MBAR();
        // ph3: slot0 (kc1,mh0)
        PH_LOAD(0, 1, 0);
        LGKM0(); SB0();
        __builtin_amdgcn_s_setprio(1); PH_MM(0); __builtin_amdgcn_s_setprio(0);
        MBAR();
        // ph4: slot0 (kc1,mh1); guard s1 B+Ah0u for ph5
        PH_LOAD(0, 1, 1);
        LGKM0(); SB0();
        __builtin_amdgcn_s_setprio(1); PH_MM(1); __builtin_amdgcn_s_setprio(0);
        VMC2(); MBAR();
        // ph5: slot1 (kc0,mh0); stage s0<-B(tile 2i+2); guard s1 Ah1u for ph6
        PH_LOAD(1, 0, 0);
        if (st) STAGE_B4(0, kof + 128);
        LGKM0(); SB0();
        __builtin_amdgcn_s_setprio(1); PH_MM(0); __builtin_amdgcn_s_setprio(0);
        if (st) { VMC4(); } else { VMC0(); }
        MBAR();
        // ph6: slot1 (kc0,mh1); stage s0<-A(tile 2i+2)
        PH_LOAD(1, 0, 1);
        if (st) STAGE_A4(0, kof + 128);
        LGKM0(); SB0();
        __builtin_amdgcn_s_setprio(1); PH_MM(1); __builtin_amdgcn_s_setprio(0);
        MBAR();
        // ph7: slot1 (kc1,mh0)
        PH_LOAD(1, 1, 0);
        LGKM0(); SB0();
        __builtin_amdgcn_s_setprio(1); PH_MM(0); __builtin_amdgcn_s_setprio(0);
        MBAR();
        // ph8: slot1 (kc1,mh1); guard s0 B+Ah0u for next ph1
        PH_LOAD(1, 1, 1);
        LGKM0(); SB0();
        __builtin_amdgcn_s_setprio(1); PH_MM(1); __builtin_amdgcn_s_setprio(0);
        if (st) { VMC2(); }
        MBAR();
    }

    short* C = Cp + (size_t)z * BB * HID;
    const int r0 = bm * 256 + wm * 128 + quad * 4;
    const int c0 = bn * 256 + wn * 64 + m16;
#pragma unroll
    for (int mt = 0; mt < 8; mt++)
#pragma unroll
        for (int nt = 0; nt < 4; nt++)
#pragma unroll
            for (int r4 = 0; r4 < 4; r4++)
                C[(size_t)(r0 + mt * 16 + r4) * HID + c0 + nt * 16] = f2bf(acc[mt][nt][r4]);
#undef STG
#undef STAGE_A4
#undef STAGE_B4
#undef PH_LOAD
#undef PH_MM
}

// ---------------- combine split-K partials + leaky + InstanceNorm, bf16 in place (D0) ----------------
__global__ __launch_bounds__(256) void rownorm_hid(short* __restrict__ D0, const short* __restrict__ D1) {
    const size_t base = (size_t)blockIdx.x * HID;
    float v[8];
    float s1 = 0.f, s2 = 0.f;
    const int c0 = threadIdx.x * 8;
    {
        s16x8 a = *(const s16x8*)&D0[base + c0];
        s16x8 b = *(const s16x8*)&D1[base + c0];
#pragma unroll
        for (int k = 0; k < 8; k++) {
            float x = lrelu(bf2f(a[k]) + bf2f(b[k]));
            v[k] = x; s1 += x; s2 += x * x;
        }
    }
#pragma unroll
    for (int o = 32; o > 0; o >>= 1) { s1 += __shfl_down(s1, o); s2 += __shfl_down(s2, o); }
    __shared__ float w1[4], w2[4];
    if ((threadIdx.x & 63) == 0) { w1[threadIdx.x >> 6] = s1; w2[threadIdx.x >> 6] = s2; }
    __syncthreads();
    s1 = w1[0] + w1[1] + w1[2] + w1[3];
    s2 = w2[0] + w2[1] + w2[2] + w2[3];
    float m = s1 * (1.f / HID);
    float inv = rsqrtf(s2 * (1.f / HID) - m * m + 1e-5f);
    s16x8 o;
#pragma unroll
    for (int k = 0; k < 8; k++) o[k] = f2bf((v[k] - m) * inv);
    *(s16x8*)&D0[base + c0] = o;
}

// ---------------- generic MFMA GEMM: A bf16 or fp32 (converted on stage), BT bf16, C fp32 ----------------
template <bool ABF16, bool LEAKY>
__global__ __launch_bounds__(256) void mfma_gemm(const float* __restrict__ Af, const short* __restrict__ Ab,
                                                 const short* __restrict__ BT,
                                                 float* __restrict__ C, int M, int Nn, int K) {
    __shared__ short As[64][40];
    __shared__ short Bs[64][40];
    const int t = threadIdx.x;
    const int bm = blockIdx.x * 64, bn = blockIdx.y * 64;
    const int wave = t >> 6, lane = t & 63;
    const int wm = (wave & 1) * 32, wn = (wave >> 1) * 32;
    const int m16 = lane & 15, quad = lane >> 4;
    const int rr = t >> 2, kk = (t & 3) * 8;
    f32x4 acc[2][2] = {};
    for (int k0 = 0; k0 < K; k0 += 32) {
        if (ABF16) {
            *(s16x8*)&As[rr][kk] = *(const s16x8*)&Ab[(size_t)(bm + rr) * K + k0 + kk];
        } else {
            const float* ap = &Af[(size_t)(bm + rr) * K + k0 + kk];
            float4 v0 = *(const float4*)ap;
            float4 v1 = *(const float4*)(ap + 4);
            s16x8 a8;
            a8[0] = f2bf(v0.x); a8[1] = f2bf(v0.y); a8[2] = f2bf(v0.z); a8[3] = f2bf(v0.w);
            a8[4] = f2bf(v1.x); a8[5] = f2bf(v1.y); a8[6] = f2bf(v1.z); a8[7] = f2bf(v1.w);
            *(s16x8*)&As[rr][kk] = a8;
        }
        *(s16x8*)&Bs[rr][kk] = *(const s16x8*)&BT[(size_t)(bn + rr) * K + k0 + kk];
        __syncthreads();
        s16x8 af[2], bfr[2];
#pragma unroll
        for (int mt = 0; mt < 2; mt++) af[mt] = *(const s16x8*)&As[wm + mt * 16 + m16][quad * 8];
#pragma unroll
        for (int nt = 0; nt < 2; nt++) bfr[nt] = *(const s16x8*)&Bs[wn + nt * 16 + m16][quad * 8];
#pragma unroll
        for (int mt = 0; mt < 2; mt++)
#pragma unroll
            for (int nt = 0; nt < 2; nt++)
                acc[mt][nt] = __builtin_amdgcn_mfma_f32_16x16x32_bf16(af[mt], bfr[nt], acc[mt][nt], 0, 0, 0);
        __syncthreads();
    }
#pragma unroll
    for (int mt = 0; mt < 2; mt++)
#pragma unroll
        for (int nt = 0; nt < 2; nt++)
#pragma unroll
            for (int r4 = 0; r4 < 4; r4++) {
                int row = bm + wm + mt * 16 + quad * 4 + r4;
                int col = bn + wn + nt * 16 + m16;
                float v = acc[mt][nt][r4];
                if (LEAKY) v = lrelu(v);
                C[(size_t)row * Nn + col] = v;
            }
}

// ---------------- per-row InstanceNorm (in place, fp32) ----------------
template <int NC>
__global__ __launch_bounds__(256) void rownorm(float* __restrict__ Y) {
    float* p = Y + (size_t)blockIdx.x * NC;
    float s1 = 0.f, s2 = 0.f;
    for (int c = threadIdx.x; c < NC; c += 256) { float v = p[c]; s1 += v; s2 += v * v; }
#pragma unroll
    for (int o = 32; o > 0; o >>= 1) { s1 += __shfl_down(s1, o); s2 += __shfl_down(s2, o); }
    __shared__ float w1[4], w2[4];
    if ((threadIdx.x & 63) == 0) { w1[threadIdx.x >> 6] = s1; w2[threadIdx.x >> 6] = s2; }
    __syncthreads();
    s1 = w1[0] + w1[1] + w1[2] + w1[3];
    s2 = w2[0] + w2[1] + w2[2] + w2[3];
    float m = s1 * (1.f / NC);
    float inv = rsqrtf(s2 * (1.f / NC) - m * m + 1e-5f);
    for (int c = threadIdx.x; c < NC; c += 256) p[c] = (p[c] - m) * inv;
}

extern "C" void kernel_launch(void* const* d_in, const int* in_sizes, int n_in,
                              void* d_out, int out_size, void* d_ws, size_t ws_size,
                              hipStream_t stream) {
    const float* x    = (const float*)d_in[0];
    const float* ew   = (const float*)d_in[1];
    const int*   src  = (const int*)d_in[2];
    const int*   dst  = (const int*)d_in[3];
    const float* W1   = (const float*)d_in[4];
    const float* W2   = (const float*)d_in[5];
    const float* a1   = (const float*)d_in[6];
    const float* g1   = (const float*)d_in[7];
    const float* b1   = (const float*)d_in[8];
    const float* a2   = (const float*)d_in[9];
    const float* g2   = (const float*)d_in[10];
    const float* b2   = (const float*)d_in[11];
    const float* Win  = (const float*)d_in[12];
    const float* Whid = (const float*)d_in[13];
    const float* Wcls = (const float*)d_in[14];
    float* out = (float*)d_out;

    // ---- workspace layout ----
    float* ro   = (float*)d_ws;                    // NN
    float* ri   = ro + NN;                         // NN
    int*   din  = (int*)(ri + NN);                 // NN (deg_in for scan)
    int*   offs = din + NN;                        // NN+4
    int*   blks = offs + NN + 4;                   // 256
    short* w1t  = (short*)(blks + 256);            // 128*64 bf16
    short* w2t  = w1t + 128 * 64;                  // 96*128 bf16
    int2*  edg  = (int2*)(((size_t)(w2t + 96 * 128) + 15) & ~(size_t)15);   // EE int2 (src, ew*ro), 16.8 MB
    short* Abf  = (short*)(edg + EE);              // 64 MiB region
    short* Bbf  = Abf + (size_t)NN * 128;          // 64 MiB region
    short* xbf  = Abf;                             // NN*64
    short* aggx = Abf + (size_t)NN * 64;           // NN*64
    // graph-build temps: u8-packed part arrays in Abf; repbase+rank in Bbf
    unsigned*       part_din   = (unsigned*)Abf;                       // NSL * NN/4 words (16 MiB)
    unsigned*       part_dout  = part_din + (size_t)NSL * (NN / 4);    // 16 MiB
    unsigned*       repbase_w  = (unsigned*)Bbf;                       // 32 MiB
    unsigned short* rankpack16 = (unsigned short*)(repbase_w + (size_t)NSL * (NN / 2));  // EE u16
    // overlays into Abf region after gather96 (h2 dead):
    short* WinT = Abf;                                      // 2048*6144 bf16 = 25165824 B
    short* D0   = (short*)((char*)Abf + 25165824);          // 4096*2048 bf16 = 16777216 B
    short* D1   = D0 + (size_t)BB * HID;                    // 4096*2048 bf16 = 16777216 B  (total 58.7 MB <= 64 MiB)
    // Y2 in edg region (edg dead after gather96):
    float* Y2   = (float*)edg;                              // 4096*512 fp32 = 8388608 B <= 16.8 MB
    // overlays into Bbf region after mlp1_mfma8 consumes gn2:
    short* WhidT = Bbf;                            // 512*2048 bf16
    short* WclsT = WhidT + (size_t)HID4 * HID;     // 256*512 bf16

    // 1) degrees + per-edge ranks via u8 LDS histograms (512 blocks, int4 streaming)
    hist_count<<<2 * 4 * NSL, 256, 0, stream>>>(dst, src, part_din, part_dout, rankpack16);
    deg_reduce<<<NN / 1024, 256, 0, stream>>>(part_din, part_dout, repbase_w, ro, ri, din);

    // 2) CSR by dst: scan + atomic-free fill
    scanA<<<NN / 1024, 256, 0, stream>>>(din, blks);
    scanB<<<1, 256, 0, stream>>>(blks, offs + NN);
    scanC<<<NN / 1024, 256, 0, stream>>>(din, blks, offs);
    fill_csr<<<EE / 256, 256, 0, stream>>>(src, dst, ew, ro, offs,
                                           (const unsigned short*)repbase_w, rankpack16, edg);

    // 3) conv layer 1: gather x (64 dims), then GEMM + fused GraphNorm1
    cvt_x<<<NN * 64 / 1024, 256, 0, stream>>>(x, xbf);
    transp_cvt<<<dim3(128 / 32, 64 / 32), 256, 0, stream>>>(W1, w1t, 64, 128);
    gather64<<<NN / 4, 256, 0, stream>>>(xbf, offs, edg, aggx);
    conv1_gn<<<NN / 128, 256, 0, stream>>>(aggx, w1t, ri, a1, g1, b1, Bbf);   // Bbf = gn1

    // 4) conv layer 2: GEMM, then wave-per-node gather, then GraphNorm2
    transp_cvt<<<dim3(96 / 32, 128 / 32), 256, 0, stream>>>(W2, w2t, 128, 96);
    conv2_mfma<<<NN / 128, 256, 0, stream>>>(Bbf, w2t, Abf);                  // h2 (xbf/aggx dead)
    gather96<<<NN / 4, 256, 0, stream>>>(Abf, offs, edg, Bbf);                // Bbf = agg2 (gn1 dead)
    graphnorm_k<96><<<BB, 256, 0, stream>>>(Bbf, ri, a2, g2, b2);             // Bbf = gn2 (MLP input)

    // 5) MLP
    transp_cvt<<<dim3(HID / 32, INMLP / 32), 256, 0, stream>>>(Win, WinT, INMLP, HID);
    mlp1_mfma8<<<256, 512, 0, stream>>>(Bbf, WinT, D0);                       // 8-phase split-K partials
    transp_cvt<<<dim3(HID4 / 32, HID / 32), 256, 0, stream>>>(Whid, WhidT, HID, HID4);
    transp_cvt<<<dim3(OUTF / 32, HID4 / 32), 256, 0, stream>>>(Wcls, WclsT, HID4, OUTF);
    rownorm_hid<<<BB, 256, 0, stream>>>(D0, D1);                                  // D0 = norm(lrelu(D0+D1)) bf16
    mfma_gemm<true, true><<<dim3(BB / 64, HID4 / 64), 256, 0, stream>>>(nullptr, D0, WhidT, Y2, BB, HID4, HID);
    rownorm<HID4><<<BB, 256, 0, stream>>>(Y2);
    mfma_gemm<false, false><<<dim3(BB / 64, OUTF / 64), 256, 0, stream>>>(Y2, nullptr, WclsT, out, BB, OUTF, HID4);
}